// Round 1
// baseline (3108.264 us; speedup 1.0000x reference)
//
#include <hip/hip_runtime.h>

#define HL 96
#define WL 96
#define HO 384
#define WO 384
#define NPIX (2*HO*WO)           // 294912 output pixels (B=2)
#define FEAT_ELEMS ((size_t)2*64*HL*WL)  // 1179648

// ---------------------------------------------------------------------------
// 3x3 SAME conv, NCHW, Cout=64. Each thread computes 4 consecutive x outputs
// for one (b, co, y). Weights for this co staged in LDS.
// ---------------------------------------------------------------------------
template<int CIN, bool RELU, bool RES>
__global__ __launch_bounds__(256) void conv3x3_k(
    const float* __restrict__ in, const float* __restrict__ wt,
    const float* __restrict__ bias, const float* __restrict__ res,
    float* __restrict__ out)
{
  __shared__ float sw[CIN * 9];
  const int t  = threadIdx.x;
  const int co = blockIdx.y;
  const int b  = blockIdx.z;
  for (int i = t; i < CIN * 9; i += 256) sw[i] = wt[(size_t)co * CIN * 9 + i];
  __syncthreads();

  const int idx4 = blockIdx.x * 256 + t;   // 0..2303
  const int y    = idx4 / 24;
  const int x0   = (idx4 % 24) * 4;

  float a0 = bias[co], a1 = a0, a2 = a0, a3 = a0;
  const float* inb = in + (size_t)b * CIN * HL * WL;

  for (int ci = 0; ci < CIN; ++ci) {
    const float* ch = inb + (size_t)ci * HL * WL;
    const float* wc = &sw[ci * 9];
    #pragma unroll
    for (int ky = 0; ky < 3; ++ky) {
      int yy = y + ky - 1;
      if (yy < 0 || yy >= HL) continue;
      const float* row = ch + yy * WL;
      float vL = (x0 > 0)       ? row[x0 - 1] : 0.f;
      float4 m = *(const float4*)(row + x0);
      float vR = (x0 + 4 < WL)  ? row[x0 + 4] : 0.f;
      float w0 = wc[ky*3+0], w1 = wc[ky*3+1], w2 = wc[ky*3+2];
      a0 += vL * w0 + m.x * w1 + m.y * w2;
      a1 += m.x * w0 + m.y * w1 + m.z * w2;
      a2 += m.y * w0 + m.z * w1 + m.w * w2;
      a3 += m.z * w0 + m.w * w1 + vR * w2;
    }
  }

  size_t o = (((size_t)b * 64 + co) * HL + y) * WL + x0;
  if (RELU) { a0 = fmaxf(a0,0.f); a1 = fmaxf(a1,0.f); a2 = fmaxf(a2,0.f); a3 = fmaxf(a3,0.f); }
  if (RES)  { a0 += res[o]; a1 += res[o+1]; a2 += res[o+2]; a3 += res[o+3]; }
  out[o] = a0; out[o+1] = a1; out[o+2] = a2; out[o+3] = a3;
}

// ---------------------------------------------------------------------------
// NCHW [2,64,96,96] -> NHWC [2,96*96,64]
// ---------------------------------------------------------------------------
__global__ __launch_bounds__(256) void nchw_to_nhwc_k(const float* __restrict__ in,
                                                      float* __restrict__ out)
{
  __shared__ float s[64][65];
  const int b = blockIdx.y;
  const int pix0 = blockIdx.x * 64;
  const int t = threadIdx.x;
  #pragma unroll
  for (int cc = 0; cc < 16; ++cc) {
    int co = cc * 4 + (t >> 6);
    int px = t & 63;
    s[px][co] = in[((size_t)b * 64 + co) * (HL*WL) + pix0 + px];
  }
  __syncthreads();
  #pragma unroll
  for (int pp = 0; pp < 16; ++pp) {
    int px = pp * 4 + (t >> 6);
    int co = t & 63;
    out[((size_t)b * (HL*WL) + pix0 + px) * 64 + co] = s[px][co];
  }
}

// ---------------------------------------------------------------------------
// MLP layer helpers (fp32, weights streamed from L2 via float4)
// ---------------------------------------------------------------------------
// dst[32][64] = act(src[32][K] @ W[K][64] + b); thread: p=t>>3, c0=(t&7)*8
__device__ __forceinline__ void layer64(const float* src, int sstride,
    const float* __restrict__ W, const float* __restrict__ B,
    float* dst, int dstride, int K, bool relu, int t)
{
  const int p  = t >> 3;
  const int c0 = (t & 7) << 3;
  float acc[8];
  #pragma unroll
  for (int j = 0; j < 8; ++j) acc[j] = B[c0 + j];
  const float* s = src + p * sstride;
  for (int k = 0; k < K; k += 4) {
    float4 a4 = *(const float4*)(s + k);
    float av[4] = {a4.x, a4.y, a4.z, a4.w};
    #pragma unroll
    for (int kk = 0; kk < 4; ++kk) {
      float a = av[kk];
      float4 w0 = *(const float4*)&W[(size_t)(k + kk) * 64 + c0];
      float4 w1 = *(const float4*)&W[(size_t)(k + kk) * 64 + c0 + 4];
      acc[0] += a * w0.x; acc[1] += a * w0.y; acc[2] += a * w0.z; acc[3] += a * w0.w;
      acc[4] += a * w1.x; acc[5] += a * w1.y; acc[6] += a * w1.z; acc[7] += a * w1.w;
    }
  }
  float* d = dst + p * dstride + c0;
  #pragma unroll
  for (int j = 0; j < 8; ++j) d[j] = relu ? fmaxf(acc[j], 0.f) : acc[j];
}

// dst[32][256] = relu(src[32][K] @ W[K][256] + b); thread: 4 px x 8 ch
__device__ __forceinline__ void layer256(const float* src, int sstride,
    const float* __restrict__ W, const float* __restrict__ B,
    float* dst, int dstride, int K, int t)
{
  const int c0 = (t & 31) << 3;   // 0..248
  const int p0 = (t >> 5) << 2;   // 0..28
  float acc[4][8];
  #pragma unroll
  for (int i = 0; i < 4; ++i)
    #pragma unroll
    for (int j = 0; j < 8; ++j) acc[i][j] = B[c0 + j];
  const float* s0 = src + p0 * sstride;
  for (int k = 0; k < K; k += 4) {
    float av[4][4];
    #pragma unroll
    for (int i = 0; i < 4; ++i) {
      float4 a4 = *(const float4*)(s0 + i * sstride + k);
      av[i][0] = a4.x; av[i][1] = a4.y; av[i][2] = a4.z; av[i][3] = a4.w;
    }
    #pragma unroll
    for (int kk = 0; kk < 4; ++kk) {
      float4 w0 = *(const float4*)&W[(size_t)(k + kk) * 256 + c0];
      float4 w1 = *(const float4*)&W[(size_t)(k + kk) * 256 + c0 + 4];
      #pragma unroll
      for (int i = 0; i < 4; ++i) {
        float a = av[i][kk];
        acc[i][0] += a * w0.x; acc[i][1] += a * w0.y;
        acc[i][2] += a * w0.z; acc[i][3] += a * w0.w;
        acc[i][4] += a * w1.x; acc[i][5] += a * w1.y;
        acc[i][6] += a * w1.z; acc[i][7] += a * w1.w;
      }
    }
  }
  #pragma unroll
  for (int i = 0; i < 4; ++i) {
    float* d = dst + (p0 + i) * dstride + c0;
    #pragma unroll
    for (int j = 0; j < 8; ++j) d[j] = fmaxf(acc[i][j], 0.f);
  }
}

// ---------------------------------------------------------------------------
// Fused per-pixel pipeline: 32 pixels per block, 256 threads
// ---------------------------------------------------------------------------
__global__ __launch_bounds__(256, 2) void fused_mlp_k(
    const float* __restrict__ featT, const float* __restrict__ coord,
    const float* __restrict__ cell,  const float* __restrict__ lr,
    const float* __restrict__ cw1, const float* __restrict__ cb1,
    const float* __restrict__ cw2, const float* __restrict__ cb2,
    const float* __restrict__ lw1, const float* __restrict__ lb1,
    const float* __restrict__ lw2, const float* __restrict__ lb2,
    const float* __restrict__ lw3, const float* __restrict__ lb3,
    const float* __restrict__ hw1, const float* __restrict__ hb1,
    const float* __restrict__ hmw, const float* __restrict__ hmb,
    const float* __restrict__ hwo, const float* __restrict__ hbo,
    float* __restrict__ out, int* __restrict__ easyCnt)
{
  __shared__ float sInp[32][72];
  __shared__ float sA[32][264];
  __shared__ float sB[32][264];
  __shared__ float sPl[32][4];
  __shared__ float sPh[32][4];
  __shared__ int   sHard[32];

  const int t  = threadIdx.x;
  const int g0 = blockIdx.x * 32;

  // ---- Phase A: build inp[32][68] ----
  {
    const int p = t & 31, q = t >> 5;        // q: 8-ch chunk
    const int g = g0 + p;
    const int b = g / (HO * WO);
    const float gy = coord[(size_t)g * 2 + 0];
    const float gx = coord[(size_t)g * 2 + 1];
    float fy = (gy + 1.f) * (HL * 0.5f) - 0.5f;
    float fx = (gx + 1.f) * (WL * 0.5f) - 0.5f;
    int iy = (int)floorf(fy + 0.5f); iy = min(max(iy, 0), HL - 1);
    int ix = (int)floorf(fx + 0.5f); ix = min(max(ix, 0), WL - 1);
    const float* fp = featT + (((size_t)b * HL * WL) + iy * WL + ix) * 64 + q * 8;
    float4 u0 = *(const float4*)fp;
    float4 u1 = *(const float4*)(fp + 4);
    *(float4*)&sInp[p][q * 8]     = u0;
    *(float4*)&sInp[p][q * 8 + 4] = u1;
    if (q == 0) {
      float cy = (2.f * iy + 1.f) / HL - 1.f;
      float cx = (2.f * ix + 1.f) / WL - 1.f;
      sInp[p][64] = (gy - cy) * HL;
      sInp[p][65] = (gx - cx) * WL;
      sInp[p][66] = cell[(size_t)g * 2 + 0] * HL;
      sInp[p][67] = cell[(size_t)g * 2 + 1] * WL;
    }
  }
  __syncthreads();

  // ---- Classifier: h = relu(inp@cw1+cb1) -> sA; gate = (l1 > l0) ----
  layer64(&sInp[0][0], 72, cw1, cb1, &sA[0][0], 264, 68, true, t);
  __syncthreads();
  if (t < 32) {
    float l0 = cb2[0], l1 = cb2[1];
    for (int c = 0; c < 64; ++c) {
      float h = sA[t][c];
      l0 += h * cw2[c * 2 + 0];
      l1 += h * cw2[c * 2 + 1];
    }
    sHard[t] = (l1 > l0) ? 1 : 0;
  }
  __syncthreads();
  if (t == 0) {
    int cnt = 0;
    for (int p = 0; p < 32; ++p) cnt += 1 - sHard[p];
    atomicAdd(easyCnt, cnt);
  }

  // ---- Light sampler ----
  layer64(&sInp[0][0], 72, lw1, lb1, &sA[0][0], 264, 68, true, t);
  __syncthreads();
  layer64(&sA[0][0], 264, lw2, lb2, &sB[0][0], 264, 64, true, t);
  __syncthreads();
  if (t < 96) {
    int p = t / 3, j = t % 3;
    float acc = lb3[j];
    for (int k = 0; k < 64; ++k) acc += sB[p][k] * lw3[k * 3 + j];
    sPl[p][j] = acc;
  }
  __syncthreads();

  // ---- Heavy sampler ----
  layer256(&sInp[0][0], 72, hw1, hb1, &sB[0][0], 264, 68, t);
  __syncthreads();
  layer256(&sB[0][0], 264, hmw,          hmb,        &sA[0][0], 264, 256, t);
  __syncthreads();
  layer256(&sA[0][0], 264, hmw + 65536,  hmb + 256,  &sB[0][0], 264, 256, t);
  __syncthreads();
  if (t < 96) {
    int p = t / 3, j = t % 3;
    float acc = hbo[j];
    for (int k = 0; k < 256; ++k) acc += sB[p][k] * hwo[k * 3 + j];
    sPh[p][j] = acc;
  }
  __syncthreads();

  // ---- Epilogue: gated select + bilinear(lr) ----
  if (t < 96) {
    int p = t / 3, ch = t % 3;
    int g = g0 + p;
    int b = g / (HO * WO);
    int rem = g % (HO * WO);
    int oy = rem / WO, ox = rem % WO;
    float gy = coord[(size_t)g * 2 + 0];
    float gx = coord[(size_t)g * 2 + 1];
    // grid = coord flipped -> (x,y) = (gx, gy)
    float x = (gx + 1.f) * (WL * 0.5f) - 0.5f;
    float y = (gy + 1.f) * (HL * 0.5f) - 0.5f;
    float xf = floorf(x), yf = floorf(y);
    float wx = x - xf, wy = y - yf;
    int x0i = min(max((int)xf,     0), WL - 1);
    int x1i = min(max((int)xf + 1, 0), WL - 1);
    int y0i = min(max((int)yf,     0), HL - 1);
    int y1i = min(max((int)yf + 1, 0), HL - 1);
    const float* img = lr + ((size_t)b * 3 + ch) * (HL * WL);
    float v00 = img[y0i * WL + x0i], v01 = img[y0i * WL + x1i];
    float v10 = img[y1i * WL + x0i], v11 = img[y1i * WL + x1i];
    float v = v00 * (1.f - wx) * (1.f - wy) + v01 * wx * (1.f - wy)
            + v10 * (1.f - wx) * wy + v11 * wx * wy;
    float pr = sHard[p] ? sPh[p][ch] : sPl[p][ch];
    out[(((size_t)b * 3 + ch) * HO + oy) * WO + ox] = pr + v;
  }
}

__global__ void finalize_k(const int* __restrict__ easyCnt, float* __restrict__ out)
{
  out[(size_t)NPIX * 3] = (float)(*easyCnt) / (float)NPIX;
}

// ---------------------------------------------------------------------------
extern "C" void kernel_launch(void* const* d_in, const int* in_sizes, int n_in,
                              void* d_out, int out_size, void* d_ws, size_t ws_size,
                              hipStream_t stream)
{
  const float* lr       = (const float*)d_in[0];
  const float* coord    = (const float*)d_in[1];
  const float* cell     = (const float*)d_in[2];
  const float* enc_w_in = (const float*)d_in[3];
  const float* enc_b_in = (const float*)d_in[4];
  const float* enc_rw   = (const float*)d_in[5];
  const float* enc_rb   = (const float*)d_in[6];
  const float* cw1      = (const float*)d_in[7];
  const float* cb1      = (const float*)d_in[8];
  const float* cw2      = (const float*)d_in[9];
  const float* cb2      = (const float*)d_in[10];
  const float* lw1      = (const float*)d_in[11];
  const float* lb1      = (const float*)d_in[12];
  const float* lw2      = (const float*)d_in[13];
  const float* lb2      = (const float*)d_in[14];
  const float* lw3      = (const float*)d_in[15];
  const float* lb3      = (const float*)d_in[16];
  const float* hw1      = (const float*)d_in[17];
  const float* hb1      = (const float*)d_in[18];
  const float* hmw      = (const float*)d_in[19];
  const float* hmb      = (const float*)d_in[20];
  const float* hwo      = (const float*)d_in[21];
  const float* hbo      = (const float*)d_in[22];
  float* out = (float*)d_out;

  char* ws = (char*)d_ws;
  int*   cnt   = (int*)ws;
  float* xA    = (float*)(ws + 1024);
  float* tmp   = xA  + FEAT_ELEMS;
  float* xB    = tmp + FEAT_ELEMS;
  float* featT = xB  + FEAT_ELEMS;
  if (ws_size < 1024 + 4 * FEAT_ELEMS * sizeof(float)) return;

  dim3 cgrid(9, 64, 2);
  conv3x3_k<3, false, false><<<cgrid, 256, 0, stream>>>(lr, enc_w_in, enc_b_in, nullptr, xA);

  float* cur = xA; float* oth = xB;
  for (int i = 0; i < 4; ++i) {
    const float* w0 = enc_rw + (size_t)i * 2 * 64 * 64 * 9;
    const float* w1 = w0 + 64 * 64 * 9;
    const float* b0 = enc_rb + i * 2 * 64;
    const float* b1 = b0 + 64;
    conv3x3_k<64, true,  false><<<cgrid, 256, 0, stream>>>(cur, w0, b0, nullptr, tmp);
    conv3x3_k<64, false, true ><<<cgrid, 256, 0, stream>>>(tmp, w1, b1, cur, oth);
    float* sw2 = cur; cur = oth; oth = sw2;
  }

  nchw_to_nhwc_k<<<dim3(144, 2), 256, 0, stream>>>(cur, featT);

  hipMemsetAsync(cnt, 0, 4, stream);
  fused_mlp_k<<<NPIX / 32, 256, 0, stream>>>(featT, coord, cell, lr,
      cw1, cb1, cw2, cb2, lw1, lb1, lw2, lb2, lw3, lb3,
      hw1, hb1, hmw, hmb, hwo, hbo, out, cnt);
  finalize_k<<<1, 1, 0, stream>>>(cnt, out);
}

// Round 2
// 1908.261 us; speedup vs baseline: 1.6288x; 1.6288x over previous
//
#include <hip/hip_runtime.h>

#define HL 96
#define WL 96
#define HO 384
#define WO 384
#define NPIX (2*HO*WO)           // 294912 output pixels (B=2)
#define FEAT_ELEMS ((size_t)2*64*HL*WL)  // 1179648

typedef unsigned short us4 __attribute__((ext_vector_type(4)));
typedef unsigned short us8 __attribute__((ext_vector_type(8)));
typedef __bf16         b8  __attribute__((ext_vector_type(8)));
typedef float          f32x4 __attribute__((ext_vector_type(4)));

__device__ __forceinline__ unsigned short f2b(float x) {
  unsigned u = __builtin_bit_cast(unsigned, x);
  unsigned r = (u + 0x7FFFu + ((u >> 16) & 1u)) >> 16;
  return (unsigned short)r;
}

__device__ __forceinline__ f32x4 MF(us8 a, us8 b, f32x4 c) {
  return __builtin_amdgcn_mfma_f32_16x16x32_bf16(
      __builtin_bit_cast(b8, a), __builtin_bit_cast(b8, b), c, 0, 0, 0);
}

// ---------------------------------------------------------------------------
// 3x3 SAME conv, NCHW, Cout=64 (unchanged from round 1 — known good)
// ---------------------------------------------------------------------------
template<int CIN, bool RELU, bool RES>
__global__ __launch_bounds__(256) void conv3x3_k(
    const float* __restrict__ in, const float* __restrict__ wt,
    const float* __restrict__ bias, const float* __restrict__ res,
    float* __restrict__ out)
{
  __shared__ float sw[CIN * 9];
  const int t  = threadIdx.x;
  const int co = blockIdx.y;
  const int b  = blockIdx.z;
  for (int i = t; i < CIN * 9; i += 256) sw[i] = wt[(size_t)co * CIN * 9 + i];
  __syncthreads();

  const int idx4 = blockIdx.x * 256 + t;
  const int y    = idx4 / 24;
  const int x0   = (idx4 % 24) * 4;

  float a0 = bias[co], a1 = a0, a2 = a0, a3 = a0;
  const float* inb = in + (size_t)b * CIN * HL * WL;

  for (int ci = 0; ci < CIN; ++ci) {
    const float* ch = inb + (size_t)ci * HL * WL;
    const float* wc = &sw[ci * 9];
    #pragma unroll
    for (int ky = 0; ky < 3; ++ky) {
      int yy = y + ky - 1;
      if (yy < 0 || yy >= HL) continue;
      const float* row = ch + yy * WL;
      float vL = (x0 > 0)       ? row[x0 - 1] : 0.f;
      float4 m = *(const float4*)(row + x0);
      float vR = (x0 + 4 < WL)  ? row[x0 + 4] : 0.f;
      float w0 = wc[ky*3+0], w1 = wc[ky*3+1], w2 = wc[ky*3+2];
      a0 += vL * w0 + m.x * w1 + m.y * w2;
      a1 += m.x * w0 + m.y * w1 + m.z * w2;
      a2 += m.y * w0 + m.z * w1 + m.w * w2;
      a3 += m.z * w0 + m.w * w1 + vR * w2;
    }
  }

  size_t o = (((size_t)b * 64 + co) * HL + y) * WL + x0;
  if (RELU) { a0 = fmaxf(a0,0.f); a1 = fmaxf(a1,0.f); a2 = fmaxf(a2,0.f); a3 = fmaxf(a3,0.f); }
  if (RES)  { a0 += res[o]; a1 += res[o+1]; a2 += res[o+2]; a3 += res[o+3]; }
  out[o] = a0; out[o+1] = a1; out[o+2] = a2; out[o+3] = a3;
}

// ---------------------------------------------------------------------------
// NCHW [2,64,96,96] -> NHWC (unchanged)
// ---------------------------------------------------------------------------
__global__ __launch_bounds__(256) void nchw_to_nhwc_k(const float* __restrict__ in,
                                                      float* __restrict__ out)
{
  __shared__ float s[64][65];
  const int b = blockIdx.y;
  const int pix0 = blockIdx.x * 64;
  const int t = threadIdx.x;
  #pragma unroll
  for (int cc = 0; cc < 16; ++cc) {
    int co = cc * 4 + (t >> 6);
    int px = t & 63;
    s[px][co] = in[((size_t)b * 64 + co) * (HL*WL) + pix0 + px];
  }
  __syncthreads();
  #pragma unroll
  for (int pp = 0; pp < 16; ++pp) {
    int px = pp * 4 + (t >> 6);
    int co = t & 63;
    out[((size_t)b * (HL*WL) + pix0 + px) * 64 + co] = s[px][co];
  }
}

// ---------------------------------------------------------------------------
// Weight prep: dst[n*Kpad + k] = bf16(src[k*N + n]), zero-padded
// ---------------------------------------------------------------------------
__global__ __launch_bounds__(256) void prep_wt_k(const float* __restrict__ src,
    unsigned short* __restrict__ dst, int K, int N, int Kpad, int Npad)
{
  int idx = blockIdx.x * 256 + threadIdx.x;
  if (idx >= Kpad * Npad) return;
  int n = idx / Kpad, k = idx - n * Kpad;
  float v = (k < K && n < N) ? src[(size_t)k * N + n] : 0.f;
  dst[idx] = f2b(v);
}

// ---------------------------------------------------------------------------
// fp32 64-wide layer (classifier only)
// ---------------------------------------------------------------------------
__device__ __forceinline__ void layer64(const float* src, int sstride,
    const float* __restrict__ W, const float* __restrict__ B,
    float* dst, int dstride, int K, bool relu, int t)
{
  const int p  = t >> 3;
  const int c0 = (t & 7) << 3;
  float acc[8];
  #pragma unroll
  for (int j = 0; j < 8; ++j) acc[j] = B[c0 + j];
  const float* s = src + p * sstride;
  for (int k = 0; k < K; k += 4) {
    float4 a4 = *(const float4*)(s + k);
    float av[4] = {a4.x, a4.y, a4.z, a4.w};
    #pragma unroll
    for (int kk = 0; kk < 4; ++kk) {
      float a = av[kk];
      float4 w0 = *(const float4*)&W[(size_t)(k + kk) * 64 + c0];
      float4 w1 = *(const float4*)&W[(size_t)(k + kk) * 64 + c0 + 4];
      acc[0] += a * w0.x; acc[1] += a * w0.y; acc[2] += a * w0.z; acc[3] += a * w0.w;
      acc[4] += a * w1.x; acc[5] += a * w1.y; acc[6] += a * w1.z; acc[7] += a * w1.w;
    }
  }
  float* d = dst + p * dstride + c0;
  #pragma unroll
  for (int j = 0; j < 8; ++j) d[j] = relu ? fmaxf(acc[j], 0.f) : acc[j];
}

// ---------------------------------------------------------------------------
// MFMA layer: out[32][N] = act(in[32][K] @ W + b) in bf16, one wave owns
// NT n-tiles starting at n0. A rows: m = mt*16 + (lane&15); k = kt*32+8*(lane>>4).
// D: row=(lane>>4)*4+r, col=lane&15  [measured m89].
// ---------------------------------------------------------------------------
template<int NT, int KT, bool RELU>
__device__ __forceinline__ void mfma_layer(
    const unsigned short* __restrict__ aIn, int aStride,
    const unsigned short* __restrict__ WT, int Kpad,
    const float* __restrict__ bias,
    unsigned short* __restrict__ aOut, int outStride,
    int n0, int lane)
{
  const int lr = lane & 15;
  const int lc = lane >> 4;
  f32x4 acc[2][NT];
  #pragma unroll
  for (int i = 0; i < 2; ++i)
    #pragma unroll
    for (int j = 0; j < NT; ++j) acc[i][j] = (f32x4){0.f, 0.f, 0.f, 0.f};

  const unsigned short* aP = aIn + lr * aStride + lc * 8;
  const unsigned short* bP = WT + (size_t)(n0 + lr) * Kpad + lc * 8;

  #pragma unroll
  for (int kt = 0; kt < KT; ++kt) {
    us8 a0 = *(const us8*)(aP + kt * 32);
    us8 a1 = *(const us8*)(aP + 16 * aStride + kt * 32);
    #pragma unroll
    for (int j = 0; j < NT; ++j) {
      us8 b = *(const us8*)(bP + (size_t)j * 16 * Kpad + kt * 32);
      acc[0][j] = MF(a0, b, acc[0][j]);
      acc[1][j] = MF(a1, b, acc[1][j]);
    }
  }

  #pragma unroll
  for (int j = 0; j < NT; ++j) {
    int n = n0 + j * 16 + lr;
    float bv = bias[n];
    #pragma unroll
    for (int mt = 0; mt < 2; ++mt)
      #pragma unroll
      for (int r = 0; r < 4; ++r) {
        float v = acc[mt][j][r] + bv;
        if (RELU) v = fmaxf(v, 0.f);
        aOut[(mt * 16 + lc * 4 + r) * outStride + n] = f2b(v);
      }
  }
}

// N=16 tile (3 real cols) -> float dst[32][4]; single wave
template<int KT>
__device__ __forceinline__ void mfma_out3(
    const unsigned short* __restrict__ aIn, int aStride,
    const unsigned short* __restrict__ WT, int Kpad,
    const float* __restrict__ bias, float (*dst)[4], int lane)
{
  const int lr = lane & 15;
  const int lc = lane >> 4;
  f32x4 acc0 = (f32x4){0.f,0.f,0.f,0.f}, acc1 = acc0;
  const unsigned short* aP = aIn + lr * aStride + lc * 8;
  const unsigned short* bP = WT + (size_t)lr * Kpad + lc * 8;
  #pragma unroll
  for (int kt = 0; kt < KT; ++kt) {
    us8 a0 = *(const us8*)(aP + kt * 32);
    us8 a1 = *(const us8*)(aP + 16 * aStride + kt * 32);
    us8 b  = *(const us8*)(bP + kt * 32);
    acc0 = MF(a0, b, acc0);
    acc1 = MF(a1, b, acc1);
  }
  if (lr < 3) {
    float bv = bias[lr];
    #pragma unroll
    for (int r = 0; r < 4; ++r) {
      dst[lc * 4 + r][lr]      = acc0[r] + bv;
      dst[16 + lc * 4 + r][lr] = acc1[r] + bv;
    }
  }
}

// ---------------------------------------------------------------------------
// Fused per-pixel pipeline: 32 pixels / block, 256 threads (4 waves)
// ---------------------------------------------------------------------------
__global__ __launch_bounds__(256, 2) void fused_mlp_k(
    const float* __restrict__ featT, const float* __restrict__ coord,
    const float* __restrict__ cell,  const float* __restrict__ lr,
    const float* __restrict__ cw1, const float* __restrict__ cb1,
    const float* __restrict__ cw2, const float* __restrict__ cb2,
    const float* __restrict__ lb1, const float* __restrict__ lb2,
    const float* __restrict__ lb3, const float* __restrict__ hb1,
    const float* __restrict__ hmb, const float* __restrict__ hbo,
    const unsigned short* __restrict__ lw1T, const unsigned short* __restrict__ lw2T,
    const unsigned short* __restrict__ lw3T, const unsigned short* __restrict__ hw1T,
    const unsigned short* __restrict__ hm0T, const unsigned short* __restrict__ hm1T,
    const unsigned short* __restrict__ hwoT,
    float* __restrict__ out, int* __restrict__ easyCnt)
{
  __shared__ float          sInp[32][72];    // fp32 inp (classifier)
  __shared__ unsigned short sInpB[32][104];  // bf16 inp, K padded to 96
  __shared__ unsigned short sAct[2][32][264];// bf16 activations ping-pong
  __shared__ float sPl[32][4];
  __shared__ float sPh[32][4];
  __shared__ int   sHard[32];

  const int t    = threadIdx.x;
  const int lane = t & 63;
  const int w    = t >> 6;
  const int g0   = blockIdx.x * 32;
  float* clsH = (float*)&sAct[0][0][0];      // fp32 [32][66], reused later

  // ---- Phase A: build inp (fp32 + bf16) ----
  {
    const int p = t & 31, q = t >> 5;
    const int g = g0 + p;
    const int b = g / (HO * WO);
    const float gy = coord[(size_t)g * 2 + 0];
    const float gx = coord[(size_t)g * 2 + 1];
    float fy = (gy + 1.f) * (HL * 0.5f) - 0.5f;
    float fx = (gx + 1.f) * (WL * 0.5f) - 0.5f;
    int iy = min(max((int)floorf(fy + 0.5f), 0), HL - 1);
    int ix = min(max((int)floorf(fx + 0.5f), 0), WL - 1);
    const float* fp = featT + (((size_t)b * HL * WL) + iy * WL + ix) * 64 + q * 8;
    float4 u0 = *(const float4*)fp;
    float4 u1 = *(const float4*)(fp + 4);
    *(float4*)&sInp[p][q * 8]     = u0;
    *(float4*)&sInp[p][q * 8 + 4] = u1;
    us8 pk;
    pk[0]=f2b(u0.x); pk[1]=f2b(u0.y); pk[2]=f2b(u0.z); pk[3]=f2b(u0.w);
    pk[4]=f2b(u1.x); pk[5]=f2b(u1.y); pk[6]=f2b(u1.z); pk[7]=f2b(u1.w);
    *(us8*)&sInpB[p][q * 8] = pk;
    if (q == 0) {
      float cy = (2.f * iy + 1.f) / HL - 1.f;
      float cx = (2.f * ix + 1.f) / WL - 1.f;
      float e0 = (gy - cy) * HL, e1 = (gx - cx) * WL;
      float e2 = cell[(size_t)g * 2 + 0] * HL, e3 = cell[(size_t)g * 2 + 1] * WL;
      sInp[p][64] = e0; sInp[p][65] = e1; sInp[p][66] = e2; sInp[p][67] = e3;
      us4 pe; pe[0]=f2b(e0); pe[1]=f2b(e1); pe[2]=f2b(e2); pe[3]=f2b(e3);
      *(us4*)&sInpB[p][64] = pe;
    }
    if (q == 1) {
      us4 z = (us4){0,0,0,0};
      #pragma unroll
      for (int c = 0; c < 7; ++c) *(us4*)&sInpB[p][68 + c * 4] = z;
    }
  }
  __syncthreads();

  // ---- Classifier (fp32, exact gate) ----
  layer64(&sInp[0][0], 72, cw1, cb1, clsH, 66, 68, true, t);
  __syncthreads();
  if (t < 32) {
    float l0 = cb2[0], l1 = cb2[1];
    for (int c = 0; c < 64; ++c) {
      float h = clsH[t * 66 + c];
      l0 += h * cw2[c * 2 + 0];
      l1 += h * cw2[c * 2 + 1];
    }
    sHard[t] = (l1 > l0) ? 1 : 0;
  }
  __syncthreads();
  if (t == 0) {
    int cnt = 0;
    for (int p = 0; p < 32; ++p) cnt += 1 - sHard[p];
    atomicAdd(easyCnt, cnt);
  }

  // ---- Light sampler (bf16 MFMA) ----
  mfma_layer<1, 3, true>(&sInpB[0][0], 104, lw1T, 96, lb1,
                         &sAct[0][0][0], 264, w * 16, lane);
  __syncthreads();
  mfma_layer<1, 2, true>(&sAct[0][0][0], 264, lw2T, 64, lb2,
                         &sAct[1][0][0], 264, w * 16, lane);
  __syncthreads();
  if (w == 0) mfma_out3<2>(&sAct[1][0][0], 264, lw3T, 64, lb3, sPl, lane);
  __syncthreads();

  // ---- Heavy sampler (bf16 MFMA) ----
  mfma_layer<4, 3, true>(&sInpB[0][0], 104, hw1T, 96, hb1,
                         &sAct[0][0][0], 264, w * 64, lane);
  __syncthreads();
  mfma_layer<4, 8, true>(&sAct[0][0][0], 264, hm0T, 256, hmb,
                         &sAct[1][0][0], 264, w * 64, lane);
  __syncthreads();
  mfma_layer<4, 8, true>(&sAct[1][0][0], 264, hm1T, 256, hmb + 256,
                         &sAct[0][0][0], 264, w * 64, lane);
  __syncthreads();
  if (w == 0) mfma_out3<8>(&sAct[0][0][0], 264, hwoT, 256, hbo, sPh, lane);
  __syncthreads();

  // ---- Epilogue: gated select + bilinear(lr) ----
  if (t < 96) {
    int p = t / 3, ch = t % 3;
    int g = g0 + p;
    int b = g / (HO * WO);
    int rem = g % (HO * WO);
    int oy = rem / WO, ox = rem % WO;
    float gy = coord[(size_t)g * 2 + 0];
    float gx = coord[(size_t)g * 2 + 1];
    float x = (gx + 1.f) * (WL * 0.5f) - 0.5f;
    float y = (gy + 1.f) * (HL * 0.5f) - 0.5f;
    float xf = floorf(x), yf = floorf(y);
    float wx = x - xf, wy = y - yf;
    int x0i = min(max((int)xf,     0), WL - 1);
    int x1i = min(max((int)xf + 1, 0), WL - 1);
    int y0i = min(max((int)yf,     0), HL - 1);
    int y1i = min(max((int)yf + 1, 0), HL - 1);
    const float* img = lr + ((size_t)b * 3 + ch) * (HL * WL);
    float v00 = img[y0i * WL + x0i], v01 = img[y0i * WL + x1i];
    float v10 = img[y1i * WL + x0i], v11 = img[y1i * WL + x1i];
    float v = v00 * (1.f - wx) * (1.f - wy) + v01 * wx * (1.f - wy)
            + v10 * (1.f - wx) * wy + v11 * wx * wy;
    float pr = sHard[p] ? sPh[p][ch] : sPl[p][ch];
    out[(((size_t)b * 3 + ch) * HO + oy) * WO + ox] = pr + v;
  }
}

__global__ void finalize_k(const int* __restrict__ easyCnt, float* __restrict__ out)
{
  out[(size_t)NPIX * 3] = (float)(*easyCnt) / (float)NPIX;
}

// ---------------------------------------------------------------------------
extern "C" void kernel_launch(void* const* d_in, const int* in_sizes, int n_in,
                              void* d_out, int out_size, void* d_ws, size_t ws_size,
                              hipStream_t stream)
{
  const float* lr       = (const float*)d_in[0];
  const float* coord    = (const float*)d_in[1];
  const float* cell     = (const float*)d_in[2];
  const float* enc_w_in = (const float*)d_in[3];
  const float* enc_b_in = (const float*)d_in[4];
  const float* enc_rw   = (const float*)d_in[5];
  const float* enc_rb   = (const float*)d_in[6];
  const float* cw1      = (const float*)d_in[7];
  const float* cb1      = (const float*)d_in[8];
  const float* cw2      = (const float*)d_in[9];
  const float* cb2      = (const float*)d_in[10];
  const float* lw1      = (const float*)d_in[11];
  const float* lb1      = (const float*)d_in[12];
  const float* lw2      = (const float*)d_in[13];
  const float* lb2      = (const float*)d_in[14];
  const float* lw3      = (const float*)d_in[15];
  const float* lb3      = (const float*)d_in[16];
  const float* hw1      = (const float*)d_in[17];
  const float* hb1      = (const float*)d_in[18];
  const float* hmw      = (const float*)d_in[19];
  const float* hmb      = (const float*)d_in[20];
  const float* hwo      = (const float*)d_in[21];
  const float* hbo      = (const float*)d_in[22];
  float* out = (float*)d_out;

  char* ws = (char*)d_ws;
  int*   cnt   = (int*)ws;
  float* xA    = (float*)(ws + 1024);
  float* tmp   = xA  + FEAT_ELEMS;
  float* xB    = tmp + FEAT_ELEMS;
  float* featT = tmp;                 // aliases tmp (free after last res conv)
  unsigned short* wb = (unsigned short*)(xB + FEAT_ELEMS);
  unsigned short* lw1T = wb;          // 64*96
  unsigned short* lw2T = lw1T + 64*96;    // 64*64
  unsigned short* lw3T = lw2T + 64*64;    // 16*64
  unsigned short* hw1T = lw3T + 16*64;    // 256*96
  unsigned short* hm0T = hw1T + 256*96;   // 256*256
  unsigned short* hm1T = hm0T + 65536;    // 256*256
  unsigned short* hwoT = hm1T + 65536;    // 16*256
  size_t need = 1024 + 3 * FEAT_ELEMS * sizeof(float)
              + (size_t)(64*96 + 64*64 + 16*64 + 256*96 + 2*65536 + 16*256) * 2;
  if (ws_size < need) return;

  // Weight prep (tiny)
  auto prep = [&](const float* s, unsigned short* d, int K, int N, int Kp, int Np) {
    int tot = Kp * Np;
    prep_wt_k<<<(tot + 255) / 256, 256, 0, stream>>>(s, d, K, N, Kp, Np);
  };
  prep(lw1, lw1T, 68, 64, 96, 64);
  prep(lw2, lw2T, 64, 64, 64, 64);
  prep(lw3, lw3T, 64, 3, 64, 16);
  prep(hw1, hw1T, 68, 256, 96, 256);
  prep(hmw,           hm0T, 256, 256, 256, 256);
  prep(hmw + 65536,   hm1T, 256, 256, 256, 256);
  prep(hwo, hwoT, 256, 3, 256, 16);

  dim3 cgrid(9, 64, 2);
  conv3x3_k<3, false, false><<<cgrid, 256, 0, stream>>>(lr, enc_w_in, enc_b_in, nullptr, xA);

  float* cur = xA; float* oth = xB;
  for (int i = 0; i < 4; ++i) {
    const float* w0 = enc_rw + (size_t)i * 2 * 64 * 64 * 9;
    const float* w1 = w0 + 64 * 64 * 9;
    const float* b0 = enc_rb + i * 2 * 64;
    const float* b1 = b0 + 64;
    conv3x3_k<64, true,  false><<<cgrid, 256, 0, stream>>>(cur, w0, b0, nullptr, tmp);
    conv3x3_k<64, false, true ><<<cgrid, 256, 0, stream>>>(tmp, w1, b1, cur, oth);
    float* sw2 = cur; cur = oth; oth = sw2;
  }

  nchw_to_nhwc_k<<<dim3(144, 2), 256, 0, stream>>>(cur, featT);

  hipMemsetAsync(cnt, 0, 4, stream);
  fused_mlp_k<<<NPIX / 32, 256, 0, stream>>>(featT, coord, cell, lr,
      cw1, cb1, cw2, cb2, lb1, lb2, lb3, hb1, hmb, hbo,
      lw1T, lw2T, lw3T, hw1T, hm0T, hm1T, hwoT, out, cnt);
  finalize_k<<<1, 1, 0, stream>>>(cnt, out);
}

// Round 3
// 839.927 us; speedup vs baseline: 3.7006x; 2.2719x over previous
//
#include <hip/hip_runtime.h>

#define HL 96
#define WL 96
#define HO 384
#define WO 384
#define NPIX (2*HO*WO)           // 294912 output pixels (B=2)
#define FEAT_ELEMS ((size_t)2*64*HL*WL)  // 1179648
#define PLANE (HL*WL)            // 9216

typedef unsigned short us4 __attribute__((ext_vector_type(4)));
typedef unsigned short us8 __attribute__((ext_vector_type(8)));
typedef __bf16         b8  __attribute__((ext_vector_type(8)));
typedef float          f32x4 __attribute__((ext_vector_type(4)));

__device__ __forceinline__ unsigned short f2b(float x) {
  unsigned u = __builtin_bit_cast(unsigned, x);
  unsigned r = (u + 0x7FFFu + ((u >> 16) & 1u)) >> 16;
  return (unsigned short)r;
}

__device__ __forceinline__ f32x4 MF(us8 a, us8 b, f32x4 c) {
  return __builtin_amdgcn_mfma_f32_16x16x32_bf16(
      __builtin_bit_cast(b8, a), __builtin_bit_cast(b8, b), c, 0, 0, 0);
}

// ---------------------------------------------------------------------------
// Scalar-weight direct conv, NCHW. lane = 1 pixel, thread = 8 output channels.
// Weights pre-transposed to [(ci*9+tap)][64] so all weight reads are
// wave-uniform -> scalar loads (free of VALU/LDS pipes).
// ---------------------------------------------------------------------------
template<int CIN, bool RELU, bool RES>
__global__ __launch_bounds__(256) void conv_s_k(
    const float* __restrict__ in,   // [B][CIN][9216]
    const float* __restrict__ wP,   // [(ci*9+tap)][64]
    const float* __restrict__ bias, // [64]
    const float* __restrict__ res,  // [B][64][9216] or null
    float* __restrict__ out)        // [B][64][9216]
{
  const int t   = threadIdx.x;
  const int p   = blockIdx.x * 256 + t;        // 0..9215
  const int co0 = blockIdx.y * 8;
  const int b   = blockIdx.z;
  const int x   = p % WL;
  const bool xl = (x == 0), xr = (x == WL - 1);

  float acc[8];
  #pragma unroll
  for (int j = 0; j < 8; ++j) acc[j] = bias[co0 + j];

  // per-ky index & validity (ci-invariant, hoisted)
  int  ic[3]; bool yv[3];
  int  im[3], ip[3];
  #pragma unroll
  for (int ky = 0; ky < 3; ++ky) {
    int pr = p + (ky - 1) * WL;
    yv[ky] = ((unsigned)pr < (unsigned)PLANE);
    ic[ky] = yv[ky] ? pr : 0;
    im[ky] = ic[ky] - 1; if (im[ky] < 0) im[ky] = 0;
    ip[ky] = ic[ky] + 1; if (ip[ky] > PLANE - 1) ip[ky] = PLANE - 1;
  }

  const float* inb = in + (size_t)b * CIN * PLANE;

  for (int ci = 0; ci < CIN; ++ci) {
    const float* pl = inb + (size_t)ci * PLANE;
    #pragma unroll
    for (int ky = 0; ky < 3; ++ky) {
      float am = pl[im[ky]];
      float a0 = pl[ic[ky]];
      float ap = pl[ip[ky]];
      if (!yv[ky]) { am = 0.f; a0 = 0.f; ap = 0.f; }
      if (xl) am = 0.f;
      if (xr) ap = 0.f;
      const float* wrow = wP + (size_t)(ci * 9 + ky * 3) * 64 + co0;
      #pragma unroll
      for (int j = 0; j < 8; ++j) acc[j] += am * wrow[j];
      #pragma unroll
      for (int j = 0; j < 8; ++j) acc[j] += a0 * wrow[64 + j];
      #pragma unroll
      for (int j = 0; j < 8; ++j) acc[j] += ap * wrow[128 + j];
    }
  }

  size_t ob = ((size_t)b * 64 + co0) * PLANE + p;
  #pragma unroll
  for (int j = 0; j < 8; ++j) {
    float v = acc[j];
    if (RELU) v = fmaxf(v, 0.f);
    if (RES)  v += res[ob + (size_t)j * PLANE];
    out[ob + (size_t)j * PLANE] = v;
  }
}

// OIHW [64][cin][3][3] -> [(ci*9+tap)][64]
__global__ __launch_bounds__(256) void prep_convw_k(const float* __restrict__ src,
                                                    float* __restrict__ dst, int cin)
{
  int idx = blockIdx.x * 256 + threadIdx.x;
  int tot = cin * 9 * 64;
  if (idx >= tot) return;
  int co = idx % 64; int r = idx / 64;   // r = ci*9+tap
  int ci = r / 9, tap = r % 9;
  dst[idx] = src[((size_t)co * cin + ci) * 9 + tap];
}

// ---------------------------------------------------------------------------
// NCHW [2,64,96,96] -> NHWC (unchanged)
// ---------------------------------------------------------------------------
__global__ __launch_bounds__(256) void nchw_to_nhwc_k(const float* __restrict__ in,
                                                      float* __restrict__ out)
{
  __shared__ float s[64][65];
  const int b = blockIdx.y;
  const int pix0 = blockIdx.x * 64;
  const int t = threadIdx.x;
  #pragma unroll
  for (int cc = 0; cc < 16; ++cc) {
    int co = cc * 4 + (t >> 6);
    int px = t & 63;
    s[px][co] = in[((size_t)b * 64 + co) * PLANE + pix0 + px];
  }
  __syncthreads();
  #pragma unroll
  for (int pp = 0; pp < 16; ++pp) {
    int px = pp * 4 + (t >> 6);
    int co = t & 63;
    out[((size_t)b * PLANE + pix0 + px) * 64 + co] = s[px][co];
  }
}

// ---------------------------------------------------------------------------
// Weight prep: dst[n*Kpad + k] = bf16(src[k*N + n]), zero-padded
// ---------------------------------------------------------------------------
__global__ __launch_bounds__(256) void prep_wt_k(const float* __restrict__ src,
    unsigned short* __restrict__ dst, int K, int N, int Kpad, int Npad)
{
  int idx = blockIdx.x * 256 + threadIdx.x;
  if (idx >= Kpad * Npad) return;
  int n = idx / Kpad, k = idx - n * Kpad;
  float v = (k < K && n < N) ? src[(size_t)k * N + n] : 0.f;
  dst[idx] = f2b(v);
}

// ---------------------------------------------------------------------------
// fp32 64-wide layer (classifier only)
// ---------------------------------------------------------------------------
__device__ __forceinline__ void layer64(const float* src, int sstride,
    const float* __restrict__ W, const float* __restrict__ B,
    float* dst, int dstride, int K, bool relu, int t)
{
  const int p  = t >> 3;
  const int c0 = (t & 7) << 3;
  float acc[8];
  #pragma unroll
  for (int j = 0; j < 8; ++j) acc[j] = B[c0 + j];
  const float* s = src + p * sstride;
  for (int k = 0; k < K; k += 4) {
    float4 a4 = *(const float4*)(s + k);
    float av[4] = {a4.x, a4.y, a4.z, a4.w};
    #pragma unroll
    for (int kk = 0; kk < 4; ++kk) {
      float a = av[kk];
      float4 w0 = *(const float4*)&W[(size_t)(k + kk) * 64 + c0];
      float4 w1 = *(const float4*)&W[(size_t)(k + kk) * 64 + c0 + 4];
      acc[0] += a * w0.x; acc[1] += a * w0.y; acc[2] += a * w0.z; acc[3] += a * w0.w;
      acc[4] += a * w1.x; acc[5] += a * w1.y; acc[6] += a * w1.z; acc[7] += a * w1.w;
    }
  }
  float* d = dst + p * dstride + c0;
  #pragma unroll
  for (int j = 0; j < 8; ++j) d[j] = relu ? fmaxf(acc[j], 0.f) : acc[j];
}

// ---------------------------------------------------------------------------
// MFMA layer helpers (unchanged from round 2 — verified)
// ---------------------------------------------------------------------------
template<int NT, int KT, bool RELU>
__device__ __forceinline__ void mfma_layer(
    const unsigned short* __restrict__ aIn, int aStride,
    const unsigned short* __restrict__ WT, int Kpad,
    const float* __restrict__ bias,
    unsigned short* __restrict__ aOut, int outStride,
    int n0, int lane)
{
  const int lr = lane & 15;
  const int lc = lane >> 4;
  f32x4 acc[2][NT];
  #pragma unroll
  for (int i = 0; i < 2; ++i)
    #pragma unroll
    for (int j = 0; j < NT; ++j) acc[i][j] = (f32x4){0.f, 0.f, 0.f, 0.f};

  const unsigned short* aP = aIn + lr * aStride + lc * 8;
  const unsigned short* bP = WT + (size_t)(n0 + lr) * Kpad + lc * 8;

  #pragma unroll
  for (int kt = 0; kt < KT; ++kt) {
    us8 a0 = *(const us8*)(aP + kt * 32);
    us8 a1 = *(const us8*)(aP + 16 * aStride + kt * 32);
    #pragma unroll
    for (int j = 0; j < NT; ++j) {
      us8 b = *(const us8*)(bP + (size_t)j * 16 * Kpad + kt * 32);
      acc[0][j] = MF(a0, b, acc[0][j]);
      acc[1][j] = MF(a1, b, acc[1][j]);
    }
  }

  #pragma unroll
  for (int j = 0; j < NT; ++j) {
    int n = n0 + j * 16 + lr;
    float bv = bias[n];
    #pragma unroll
    for (int mt = 0; mt < 2; ++mt)
      #pragma unroll
      for (int r = 0; r < 4; ++r) {
        float v = acc[mt][j][r] + bv;
        if (RELU) v = fmaxf(v, 0.f);
        aOut[(mt * 16 + lc * 4 + r) * outStride + n] = f2b(v);
      }
  }
}

template<int KT>
__device__ __forceinline__ void mfma_out3(
    const unsigned short* __restrict__ aIn, int aStride,
    const unsigned short* __restrict__ WT, int Kpad,
    const float* __restrict__ bias, float (*dst)[4], int lane)
{
  const int lr = lane & 15;
  const int lc = lane >> 4;
  f32x4 acc0 = (f32x4){0.f,0.f,0.f,0.f}, acc1 = acc0;
  const unsigned short* aP = aIn + lr * aStride + lc * 8;
  const unsigned short* bP = WT + (size_t)lr * Kpad + lc * 8;
  #pragma unroll
  for (int kt = 0; kt < KT; ++kt) {
    us8 a0 = *(const us8*)(aP + kt * 32);
    us8 a1 = *(const us8*)(aP + 16 * aStride + kt * 32);
    us8 b  = *(const us8*)(bP + kt * 32);
    acc0 = MF(a0, b, acc0);
    acc1 = MF(a1, b, acc1);
  }
  if (lr < 3) {
    float bv = bias[lr];
    #pragma unroll
    for (int r = 0; r < 4; ++r) {
      dst[lc * 4 + r][lr]      = acc0[r] + bv;
      dst[16 + lc * 4 + r][lr] = acc1[r] + bv;
    }
  }
}

// ---------------------------------------------------------------------------
// Fused per-pixel pipeline (unchanged from round 2 — verified)
// ---------------------------------------------------------------------------
__global__ __launch_bounds__(256, 2) void fused_mlp_k(
    const float* __restrict__ featT, const float* __restrict__ coord,
    const float* __restrict__ cell,  const float* __restrict__ lr,
    const float* __restrict__ cw1, const float* __restrict__ cb1,
    const float* __restrict__ cw2, const float* __restrict__ cb2,
    const float* __restrict__ lb1, const float* __restrict__ lb2,
    const float* __restrict__ lb3, const float* __restrict__ hb1,
    const float* __restrict__ hmb, const float* __restrict__ hbo,
    const unsigned short* __restrict__ lw1T, const unsigned short* __restrict__ lw2T,
    const unsigned short* __restrict__ lw3T, const unsigned short* __restrict__ hw1T,
    const unsigned short* __restrict__ hm0T, const unsigned short* __restrict__ hm1T,
    const unsigned short* __restrict__ hwoT,
    float* __restrict__ out, int* __restrict__ easyCnt)
{
  __shared__ float          sInp[32][72];
  __shared__ unsigned short sInpB[32][104];
  __shared__ unsigned short sAct[2][32][264];
  __shared__ float sPl[32][4];
  __shared__ float sPh[32][4];
  __shared__ int   sHard[32];

  const int t    = threadIdx.x;
  const int lane = t & 63;
  const int w    = t >> 6;
  const int g0   = blockIdx.x * 32;
  float* clsH = (float*)&sAct[0][0][0];

  {
    const int p = t & 31, q = t >> 5;
    const int g = g0 + p;
    const int b = g / (HO * WO);
    const float gy = coord[(size_t)g * 2 + 0];
    const float gx = coord[(size_t)g * 2 + 1];
    float fy = (gy + 1.f) * (HL * 0.5f) - 0.5f;
    float fx = (gx + 1.f) * (WL * 0.5f) - 0.5f;
    int iy = min(max((int)floorf(fy + 0.5f), 0), HL - 1);
    int ix = min(max((int)floorf(fx + 0.5f), 0), WL - 1);
    const float* fp = featT + (((size_t)b * HL * WL) + iy * WL + ix) * 64 + q * 8;
    float4 u0 = *(const float4*)fp;
    float4 u1 = *(const float4*)(fp + 4);
    *(float4*)&sInp[p][q * 8]     = u0;
    *(float4*)&sInp[p][q * 8 + 4] = u1;
    us8 pk;
    pk[0]=f2b(u0.x); pk[1]=f2b(u0.y); pk[2]=f2b(u0.z); pk[3]=f2b(u0.w);
    pk[4]=f2b(u1.x); pk[5]=f2b(u1.y); pk[6]=f2b(u1.z); pk[7]=f2b(u1.w);
    *(us8*)&sInpB[p][q * 8] = pk;
    if (q == 0) {
      float cy = (2.f * iy + 1.f) / HL - 1.f;
      float cx = (2.f * ix + 1.f) / WL - 1.f;
      float e0 = (gy - cy) * HL, e1 = (gx - cx) * WL;
      float e2 = cell[(size_t)g * 2 + 0] * HL, e3 = cell[(size_t)g * 2 + 1] * WL;
      sInp[p][64] = e0; sInp[p][65] = e1; sInp[p][66] = e2; sInp[p][67] = e3;
      us4 pe; pe[0]=f2b(e0); pe[1]=f2b(e1); pe[2]=f2b(e2); pe[3]=f2b(e3);
      *(us4*)&sInpB[p][64] = pe;
    }
    if (q == 1) {
      us4 z = (us4){0,0,0,0};
      #pragma unroll
      for (int c = 0; c < 7; ++c) *(us4*)&sInpB[p][68 + c * 4] = z;
    }
  }
  __syncthreads();

  layer64(&sInp[0][0], 72, cw1, cb1, clsH, 66, 68, true, t);
  __syncthreads();
  if (t < 32) {
    float l0 = cb2[0], l1 = cb2[1];
    for (int c = 0; c < 64; ++c) {
      float h = clsH[t * 66 + c];
      l0 += h * cw2[c * 2 + 0];
      l1 += h * cw2[c * 2 + 1];
    }
    sHard[t] = (l1 > l0) ? 1 : 0;
  }
  __syncthreads();
  if (t == 0) {
    int cnt = 0;
    for (int p = 0; p < 32; ++p) cnt += 1 - sHard[p];
    atomicAdd(easyCnt, cnt);
  }

  mfma_layer<1, 3, true>(&sInpB[0][0], 104, lw1T, 96, lb1,
                         &sAct[0][0][0], 264, w * 16, lane);
  __syncthreads();
  mfma_layer<1, 2, true>(&sAct[0][0][0], 264, lw2T, 64, lb2,
                         &sAct[1][0][0], 264, w * 16, lane);
  __syncthreads();
  if (w == 0) mfma_out3<2>(&sAct[1][0][0], 264, lw3T, 64, lb3, sPl, lane);
  __syncthreads();

  mfma_layer<4, 3, true>(&sInpB[0][0], 104, hw1T, 96, hb1,
                         &sAct[0][0][0], 264, w * 64, lane);
  __syncthreads();
  mfma_layer<4, 8, true>(&sAct[0][0][0], 264, hm0T, 256, hmb,
                         &sAct[1][0][0], 264, w * 64, lane);
  __syncthreads();
  mfma_layer<4, 8, true>(&sAct[1][0][0], 264, hm1T, 256, hmb + 256,
                         &sAct[0][0][0], 264, w * 64, lane);
  __syncthreads();
  if (w == 0) mfma_out3<8>(&sAct[0][0][0], 264, hwoT, 256, hbo, sPh, lane);
  __syncthreads();

  if (t < 96) {
    int p = t / 3, ch = t % 3;
    int g = g0 + p;
    int b = g / (HO * WO);
    int rem = g % (HO * WO);
    int oy = rem / WO, ox = rem % WO;
    float gy = coord[(size_t)g * 2 + 0];
    float gx = coord[(size_t)g * 2 + 1];
    float x = (gx + 1.f) * (WL * 0.5f) - 0.5f;
    float y = (gy + 1.f) * (HL * 0.5f) - 0.5f;
    float xf = floorf(x), yf = floorf(y);
    float wx = x - xf, wy = y - yf;
    int x0i = min(max((int)xf,     0), WL - 1);
    int x1i = min(max((int)xf + 1, 0), WL - 1);
    int y0i = min(max((int)yf,     0), HL - 1);
    int y1i = min(max((int)yf + 1, 0), HL - 1);
    const float* img = lr + ((size_t)b * 3 + ch) * (HL * WL);
    float v00 = img[y0i * WL + x0i], v01 = img[y0i * WL + x1i];
    float v10 = img[y1i * WL + x0i], v11 = img[y1i * WL + x1i];
    float v = v00 * (1.f - wx) * (1.f - wy) + v01 * wx * (1.f - wy)
            + v10 * (1.f - wx) * wy + v11 * wx * wy;
    float pr = sHard[p] ? sPh[p][ch] : sPl[p][ch];
    out[(((size_t)b * 3 + ch) * HO + oy) * WO + ox] = pr + v;
  }
}

__global__ void finalize_k(const int* __restrict__ easyCnt, float* __restrict__ out)
{
  out[(size_t)NPIX * 3] = (float)(*easyCnt) / (float)NPIX;
}

// ---------------------------------------------------------------------------
extern "C" void kernel_launch(void* const* d_in, const int* in_sizes, int n_in,
                              void* d_out, int out_size, void* d_ws, size_t ws_size,
                              hipStream_t stream)
{
  const float* lr       = (const float*)d_in[0];
  const float* coord    = (const float*)d_in[1];
  const float* cell     = (const float*)d_in[2];
  const float* enc_w_in = (const float*)d_in[3];
  const float* enc_b_in = (const float*)d_in[4];
  const float* enc_rw   = (const float*)d_in[5];
  const float* enc_rb   = (const float*)d_in[6];
  const float* cw1      = (const float*)d_in[7];
  const float* cb1      = (const float*)d_in[8];
  const float* cw2      = (const float*)d_in[9];
  const float* cb2      = (const float*)d_in[10];
  const float* lw1      = (const float*)d_in[11];
  const float* lb1      = (const float*)d_in[12];
  const float* lw2      = (const float*)d_in[13];
  const float* lb2      = (const float*)d_in[14];
  const float* lw3      = (const float*)d_in[15];
  const float* lb3      = (const float*)d_in[16];
  const float* hw1      = (const float*)d_in[17];
  const float* hb1      = (const float*)d_in[18];
  const float* hmw      = (const float*)d_in[19];
  const float* hmb      = (const float*)d_in[20];
  const float* hwo      = (const float*)d_in[21];
  const float* hbo      = (const float*)d_in[22];
  float* out = (float*)d_out;

  char* ws = (char*)d_ws;
  int*   cnt   = (int*)ws;
  float* xA    = (float*)(ws + 1024);
  float* tmp   = xA  + FEAT_ELEMS;
  float* xB    = tmp + FEAT_ELEMS;
  float* featT = tmp;                 // aliases tmp (free after last res conv)
  unsigned short* wb = (unsigned short*)(xB + FEAT_ELEMS);
  unsigned short* lw1T = wb;              // 64*96
  unsigned short* lw2T = lw1T + 64*96;    // 64*64
  unsigned short* lw3T = lw2T + 64*64;    // 16*64
  unsigned short* hw1T = lw3T + 16*64;    // 256*96
  unsigned short* hm0T = hw1T + 256*96;   // 256*256
  unsigned short* hm1T = hm0T + 65536;    // 256*256
  unsigned short* hwoT = hm1T + 65536;    // 16*256
  const size_t nb16 = 64*96 + 64*64 + 16*64 + 256*96 + 2*65536 + 16*256; // 171008
  float* cwIn  = (float*)(wb + nb16);     // 27*64 = 1728
  float* cwRes = cwIn + 1728;             // 8 * 36864
  size_t need = 1024 + 3 * FEAT_ELEMS * sizeof(float)
              + nb16 * 2 + (1728 + 8 * 36864) * sizeof(float);
  if (ws_size < need) return;

  // --- weight preps ---
  auto prep = [&](const float* s, unsigned short* d, int K, int N, int Kp, int Np) {
    int tot = Kp * Np;
    prep_wt_k<<<(tot + 255) / 256, 256, 0, stream>>>(s, d, K, N, Kp, Np);
  };
  prep(lw1, lw1T, 68, 64, 96, 64);
  prep(lw2, lw2T, 64, 64, 64, 64);
  prep(lw3, lw3T, 64, 3, 64, 16);
  prep(hw1, hw1T, 68, 256, 96, 256);
  prep(hmw,         hm0T, 256, 256, 256, 256);
  prep(hmw + 65536, hm1T, 256, 256, 256, 256);
  prep(hwo, hwoT, 256, 3, 256, 16);

  prep_convw_k<<<(1728 + 255) / 256, 256, 0, stream>>>(enc_w_in, cwIn, 3);
  for (int l = 0; l < 8; ++l)
    prep_convw_k<<<(36864 + 255) / 256, 256, 0, stream>>>(
        enc_rw + (size_t)l * 36864, cwRes + (size_t)l * 36864, 64);

  // --- encoder ---
  dim3 cgrid(36, 8, 2);
  conv_s_k<3, false, false><<<cgrid, 256, 0, stream>>>(lr, cwIn, enc_b_in, nullptr, xA);

  float* cur = xA; float* oth = xB;
  for (int i = 0; i < 4; ++i) {
    const float* wp0 = cwRes + (size_t)(2 * i)     * 36864;
    const float* wp1 = cwRes + (size_t)(2 * i + 1) * 36864;
    const float* b0 = enc_rb + i * 128;
    const float* b1 = b0 + 64;
    conv_s_k<64, true,  false><<<cgrid, 256, 0, stream>>>(cur, wp0, b0, nullptr, tmp);
    conv_s_k<64, false, true ><<<cgrid, 256, 0, stream>>>(tmp, wp1, b1, cur, oth);
    float* sw2 = cur; cur = oth; oth = sw2;
  }

  nchw_to_nhwc_k<<<dim3(144, 2), 256, 0, stream>>>(cur, featT);

  hipMemsetAsync(cnt, 0, 4, stream);
  fused_mlp_k<<<NPIX / 32, 256, 0, stream>>>(featT, coord, cell, lr,
      cw1, cb1, cw2, cb2, lb1, lb2, lb3, hb1, hmb, hbo,
      lw1T, lw2T, lw3T, hw1T, hm0T, hm1T, hwoT, out, cnt);
  finalize_k<<<1, 1, 0, stream>>>(cnt, out);
}

// Round 4
// 821.958 us; speedup vs baseline: 3.7815x; 1.0219x over previous
//
#include <hip/hip_runtime.h>

#define HL 96
#define WL 96
#define HO 384
#define WO 384
#define NPIX (2*HO*WO)           // 294912 output pixels (B=2)
#define FEAT_ELEMS ((size_t)2*64*HL*WL)  // 1179648
#define PLANE (HL*WL)            // 9216

typedef unsigned short us4 __attribute__((ext_vector_type(4)));
typedef unsigned short us8 __attribute__((ext_vector_type(8)));
typedef __bf16         b8  __attribute__((ext_vector_type(8)));
typedef float          f32x4 __attribute__((ext_vector_type(4)));

__device__ __forceinline__ unsigned short f2b(float x) {
  unsigned u = __builtin_bit_cast(unsigned, x);
  unsigned r = (u + 0x7FFFu + ((u >> 16) & 1u)) >> 16;
  return (unsigned short)r;
}

__device__ __forceinline__ f32x4 MF(us8 a, us8 b, f32x4 c) {
  return __builtin_amdgcn_mfma_f32_16x16x32_bf16(
      __builtin_bit_cast(b8, a), __builtin_bit_cast(b8, b), c, 0, 0, 0);
}

// ---------------------------------------------------------------------------
// Scalar-weight direct conv, NCHW. lane = 1 pixel, thread = COPT out channels.
// ---------------------------------------------------------------------------
template<int CIN, int COPT, bool RELU, bool RES>
__global__ __launch_bounds__(256) void conv_s_k(
    const float* __restrict__ in,   // [B][CIN][9216]
    const float* __restrict__ wP,   // [(ci*9+tap)][64]
    const float* __restrict__ bias, // [64]
    const float* __restrict__ res,  // [B][64][9216] or null
    float* __restrict__ out)        // [B][64][9216]
{
  const int t   = threadIdx.x;
  const int p   = blockIdx.x * 256 + t;        // 0..9215
  const int co0 = blockIdx.y * COPT;
  const int b   = blockIdx.z;
  const int x   = p % WL;
  const bool xl = (x == 0), xr = (x == WL - 1);

  float acc[COPT];
  #pragma unroll
  for (int j = 0; j < COPT; ++j) acc[j] = bias[co0 + j];

  int  ic[3]; bool yv[3];
  int  im[3], ip[3];
  #pragma unroll
  for (int ky = 0; ky < 3; ++ky) {
    int pr = p + (ky - 1) * WL;
    yv[ky] = ((unsigned)pr < (unsigned)PLANE);
    ic[ky] = yv[ky] ? pr : 0;
    im[ky] = ic[ky] - 1; if (im[ky] < 0) im[ky] = 0;
    ip[ky] = ic[ky] + 1; if (ip[ky] > PLANE - 1) ip[ky] = PLANE - 1;
  }

  const float* inb = in + (size_t)b * CIN * PLANE;

  for (int ci = 0; ci < CIN; ++ci) {
    const float* pl = inb + (size_t)ci * PLANE;
    #pragma unroll
    for (int ky = 0; ky < 3; ++ky) {
      float am = pl[im[ky]];
      float a0 = pl[ic[ky]];
      float ap = pl[ip[ky]];
      if (!yv[ky]) { am = 0.f; a0 = 0.f; ap = 0.f; }
      if (xl) am = 0.f;
      if (xr) ap = 0.f;
      const float* wrow = wP + (size_t)(ci * 9 + ky * 3) * 64 + co0;
      #pragma unroll
      for (int j = 0; j < COPT; ++j) acc[j] += am * wrow[j];
      #pragma unroll
      for (int j = 0; j < COPT; ++j) acc[j] += a0 * wrow[64 + j];
      #pragma unroll
      for (int j = 0; j < COPT; ++j) acc[j] += ap * wrow[128 + j];
    }
  }

  size_t ob = ((size_t)b * 64 + co0) * PLANE + p;
  #pragma unroll
  for (int j = 0; j < COPT; ++j) {
    float v = acc[j];
    if (RELU) v = fmaxf(v, 0.f);
    if (RES)  v += res[ob + (size_t)j * PLANE];
    out[ob + (size_t)j * PLANE] = v;
  }
}

// OIHW [64][cin][3][3] -> [(ci*9+tap)][64]
__global__ __launch_bounds__(256) void prep_convw_k(const float* __restrict__ src,
                                                    float* __restrict__ dst, int cin)
{
  int idx = blockIdx.x * 256 + threadIdx.x;
  int tot = cin * 9 * 64;
  if (idx >= tot) return;
  int co = idx % 64; int r = idx / 64;   // r = ci*9+tap
  int ci = r / 9, tap = r % 9;
  dst[idx] = src[((size_t)co * cin + ci) * 9 + tap];
}

// ---------------------------------------------------------------------------
// NCHW [2,64,96,96] -> NHWC
// ---------------------------------------------------------------------------
__global__ __launch_bounds__(256) void nchw_to_nhwc_k(const float* __restrict__ in,
                                                      float* __restrict__ out)
{
  __shared__ float s[64][65];
  const int b = blockIdx.y;
  const int pix0 = blockIdx.x * 64;
  const int t = threadIdx.x;
  #pragma unroll
  for (int cc = 0; cc < 16; ++cc) {
    int co = cc * 4 + (t >> 6);
    int px = t & 63;
    s[px][co] = in[((size_t)b * 64 + co) * PLANE + pix0 + px];
  }
  __syncthreads();
  #pragma unroll
  for (int pp = 0; pp < 16; ++pp) {
    int px = pp * 4 + (t >> 6);
    int co = t & 63;
    out[((size_t)b * PLANE + pix0 + px) * 64 + co] = s[px][co];
  }
}

// ---------------------------------------------------------------------------
// Weight prep: dst[n*Kpad + k] = bf16(src[k*N + n]), zero-padded
// ---------------------------------------------------------------------------
__global__ __launch_bounds__(256) void prep_wt_k(const float* __restrict__ src,
    unsigned short* __restrict__ dst, int K, int N, int Kpad, int Npad)
{
  int idx = blockIdx.x * 256 + threadIdx.x;
  if (idx >= Kpad * Npad) return;
  int n = idx / Kpad, k = idx - n * Kpad;
  float v = (k < K && n < N) ? src[(size_t)k * N + n] : 0.f;
  dst[idx] = f2b(v);
}

// ---------------------------------------------------------------------------
// fp32 64-wide layer (classifier only)
// ---------------------------------------------------------------------------
__device__ __forceinline__ void layer64(const float* src, int sstride,
    const float* __restrict__ W, const float* __restrict__ B,
    float* dst, int dstride, int K, bool relu, int t)
{
  const int p  = t >> 3;
  const int c0 = (t & 7) << 3;
  float acc[8];
  #pragma unroll
  for (int j = 0; j < 8; ++j) acc[j] = B[c0 + j];
  const float* s = src + p * sstride;
  for (int k = 0; k < K; k += 4) {
    float4 a4 = *(const float4*)(s + k);
    float av[4] = {a4.x, a4.y, a4.z, a4.w};
    #pragma unroll
    for (int kk = 0; kk < 4; ++kk) {
      float a = av[kk];
      float4 w0 = *(const float4*)&W[(size_t)(k + kk) * 64 + c0];
      float4 w1 = *(const float4*)&W[(size_t)(k + kk) * 64 + c0 + 4];
      acc[0] += a * w0.x; acc[1] += a * w0.y; acc[2] += a * w0.z; acc[3] += a * w0.w;
      acc[4] += a * w1.x; acc[5] += a * w1.y; acc[6] += a * w1.z; acc[7] += a * w1.w;
    }
  }
  float* d = dst + p * dstride + c0;
  #pragma unroll
  for (int j = 0; j < 8; ++j) d[j] = relu ? fmaxf(acc[j], 0.f) : acc[j];
}

// ---------------------------------------------------------------------------
// MFMA layer, register-batched loads: preload a K-chunk of B (and A) into
// registers with ONE wait, then stream MFMAs from registers. Collapses the
// per-load L2 latency chain that made round-2/3's version latency-bound.
// ---------------------------------------------------------------------------
template<int NT, int KT, bool RELU>
__device__ __forceinline__ void mfma_layer(
    const unsigned short* __restrict__ aIn, int aStride,
    const unsigned short* __restrict__ WT, int Kpad,
    const float* __restrict__ bias,
    unsigned short* __restrict__ aOut, int outStride,
    int n0, int lane)
{
  const int lr = lane & 15;
  const int lc = lane >> 4;
  f32x4 acc[2][NT];
  #pragma unroll
  for (int i = 0; i < 2; ++i)
    #pragma unroll
    for (int j = 0; j < NT; ++j) acc[i][j] = (f32x4){0.f, 0.f, 0.f, 0.f};

  const unsigned short* aP = aIn + lr * aStride + lc * 8;
  const unsigned short* bP = WT + (size_t)(n0 + lr) * Kpad + lc * 8;

  constexpr int KC = (KT >= 4) ? 4 : KT;   // 8->4+4, 3->3, 2->2
  #pragma unroll
  for (int kc = 0; kc < KT; kc += KC) {
    us8 breg[KC][NT];
    #pragma unroll
    for (int kk = 0; kk < KC; ++kk)
      #pragma unroll
      for (int j = 0; j < NT; ++j)
        breg[kk][j] = *(const us8*)(bP + (size_t)j * 16 * Kpad + (kc + kk) * 32);
    us8 areg[KC][2];
    #pragma unroll
    for (int kk = 0; kk < KC; ++kk) {
      areg[kk][0] = *(const us8*)(aP + (kc + kk) * 32);
      areg[kk][1] = *(const us8*)(aP + 16 * aStride + (kc + kk) * 32);
    }
    #pragma unroll
    for (int kk = 0; kk < KC; ++kk)
      #pragma unroll
      for (int j = 0; j < NT; ++j) {
        acc[0][j] = MF(areg[kk][0], breg[kk][j], acc[0][j]);
        acc[1][j] = MF(areg[kk][1], breg[kk][j], acc[1][j]);
      }
  }

  #pragma unroll
  for (int j = 0; j < NT; ++j) {
    int n = n0 + j * 16 + lr;
    float bv = bias[n];
    #pragma unroll
    for (int mt = 0; mt < 2; ++mt)
      #pragma unroll
      for (int r = 0; r < 4; ++r) {
        float v = acc[mt][j][r] + bv;
        if (RELU) v = fmaxf(v, 0.f);
        aOut[(mt * 16 + lc * 4 + r) * outStride + n] = f2b(v);
      }
  }
}

template<int KT>
__device__ __forceinline__ void mfma_out3(
    const unsigned short* __restrict__ aIn, int aStride,
    const unsigned short* __restrict__ WT, int Kpad,
    const float* __restrict__ bias, float (*dst)[4], int lane)
{
  const int lr = lane & 15;
  const int lc = lane >> 4;
  f32x4 acc0 = (f32x4){0.f,0.f,0.f,0.f}, acc1 = acc0;
  const unsigned short* aP = aIn + lr * aStride + lc * 8;
  const unsigned short* bP = WT + (size_t)lr * Kpad + lc * 8;

  constexpr int KC = (KT >= 4) ? 4 : KT;
  #pragma unroll
  for (int kc = 0; kc < KT; kc += KC) {
    us8 breg[KC];
    #pragma unroll
    for (int kk = 0; kk < KC; ++kk)
      breg[kk] = *(const us8*)(bP + (kc + kk) * 32);
    us8 areg[KC][2];
    #pragma unroll
    for (int kk = 0; kk < KC; ++kk) {
      areg[kk][0] = *(const us8*)(aP + (kc + kk) * 32);
      areg[kk][1] = *(const us8*)(aP + 16 * aStride + (kc + kk) * 32);
    }
    #pragma unroll
    for (int kk = 0; kk < KC; ++kk) {
      acc0 = MF(areg[kk][0], breg[kk], acc0);
      acc1 = MF(areg[kk][1], breg[kk], acc1);
    }
  }
  if (lr < 3) {
    float bv = bias[lr];
    #pragma unroll
    for (int r = 0; r < 4; ++r) {
      dst[lc * 4 + r][lr]      = acc0[r] + bv;
      dst[16 + lc * 4 + r][lr] = acc1[r] + bv;
    }
  }
}

// ---------------------------------------------------------------------------
// Fused per-pixel pipeline: 32 pixels / block, 256 threads (4 waves)
// ---------------------------------------------------------------------------
__global__ __launch_bounds__(256, 3) void fused_mlp_k(
    const float* __restrict__ featT, const float* __restrict__ coord,
    const float* __restrict__ cell,  const float* __restrict__ lr,
    const float* __restrict__ cw1, const float* __restrict__ cb1,
    const float* __restrict__ cw2, const float* __restrict__ cb2,
    const float* __restrict__ lb1, const float* __restrict__ lb2,
    const float* __restrict__ lb3, const float* __restrict__ hb1,
    const float* __restrict__ hmb, const float* __restrict__ hbo,
    const unsigned short* __restrict__ lw1T, const unsigned short* __restrict__ lw2T,
    const unsigned short* __restrict__ lw3T, const unsigned short* __restrict__ hw1T,
    const unsigned short* __restrict__ hm0T, const unsigned short* __restrict__ hm1T,
    const unsigned short* __restrict__ hwoT,
    float* __restrict__ out, int* __restrict__ easyCnt)
{
  __shared__ float          sInp[32][72];
  __shared__ unsigned short sInpB[32][104];
  __shared__ unsigned short sAct[2][32][264];
  __shared__ float sPl[32][4];
  __shared__ float sPh[32][4];
  __shared__ int   sHard[32];

  const int t    = threadIdx.x;
  const int lane = t & 63;
  const int w    = t >> 6;
  const int g0   = blockIdx.x * 32;
  float* clsH = (float*)&sAct[0][0][0];

  {
    const int p = t & 31, q = t >> 5;
    const int g = g0 + p;
    const int b = g / (HO * WO);
    const float gy = coord[(size_t)g * 2 + 0];
    const float gx = coord[(size_t)g * 2 + 1];
    float fy = (gy + 1.f) * (HL * 0.5f) - 0.5f;
    float fx = (gx + 1.f) * (WL * 0.5f) - 0.5f;
    int iy = min(max((int)floorf(fy + 0.5f), 0), HL - 1);
    int ix = min(max((int)floorf(fx + 0.5f), 0), WL - 1);
    const float* fp = featT + (((size_t)b * HL * WL) + iy * WL + ix) * 64 + q * 8;
    float4 u0 = *(const float4*)fp;
    float4 u1 = *(const float4*)(fp + 4);
    *(float4*)&sInp[p][q * 8]     = u0;
    *(float4*)&sInp[p][q * 8 + 4] = u1;
    us8 pk;
    pk[0]=f2b(u0.x); pk[1]=f2b(u0.y); pk[2]=f2b(u0.z); pk[3]=f2b(u0.w);
    pk[4]=f2b(u1.x); pk[5]=f2b(u1.y); pk[6]=f2b(u1.z); pk[7]=f2b(u1.w);
    *(us8*)&sInpB[p][q * 8] = pk;
    if (q == 0) {
      float cy = (2.f * iy + 1.f) / HL - 1.f;
      float cx = (2.f * ix + 1.f) / WL - 1.f;
      float e0 = (gy - cy) * HL, e1 = (gx - cx) * WL;
      float e2 = cell[(size_t)g * 2 + 0] * HL, e3 = cell[(size_t)g * 2 + 1] * WL;
      sInp[p][64] = e0; sInp[p][65] = e1; sInp[p][66] = e2; sInp[p][67] = e3;
      us4 pe; pe[0]=f2b(e0); pe[1]=f2b(e1); pe[2]=f2b(e2); pe[3]=f2b(e3);
      *(us4*)&sInpB[p][64] = pe;
    }
    if (q == 1) {
      us4 z = (us4){0,0,0,0};
      #pragma unroll
      for (int c = 0; c < 7; ++c) *(us4*)&sInpB[p][68 + c * 4] = z;
    }
  }
  __syncthreads();

  layer64(&sInp[0][0], 72, cw1, cb1, clsH, 66, 68, true, t);
  __syncthreads();
  if (t < 32) {
    float l0 = cb2[0], l1 = cb2[1];
    for (int c = 0; c < 64; ++c) {
      float h = clsH[t * 66 + c];
      l0 += h * cw2[c * 2 + 0];
      l1 += h * cw2[c * 2 + 1];
    }
    sHard[t] = (l1 > l0) ? 1 : 0;
  }
  __syncthreads();
  if (t == 0) {
    int cnt = 0;
    for (int p = 0; p < 32; ++p) cnt += 1 - sHard[p];
    atomicAdd(easyCnt, cnt);
  }

  mfma_layer<1, 3, true>(&sInpB[0][0], 104, lw1T, 96, lb1,
                         &sAct[0][0][0], 264, w * 16, lane);
  __syncthreads();
  mfma_layer<1, 2, true>(&sAct[0][0][0], 264, lw2T, 64, lb2,
                         &sAct[1][0][0], 264, w * 16, lane);
  __syncthreads();
  if (w == 0) mfma_out3<2>(&sAct[1][0][0], 264, lw3T, 64, lb3, sPl, lane);
  __syncthreads();

  mfma_layer<4, 3, true>(&sInpB[0][0], 104, hw1T, 96, hb1,
                         &sAct[0][0][0], 264, w * 64, lane);
  __syncthreads();
  mfma_layer<4, 8, true>(&sAct[0][0][0], 264, hm0T, 256, hmb,
                         &sAct[1][0][0], 264, w * 64, lane);
  __syncthreads();
  mfma_layer<4, 8, true>(&sAct[1][0][0], 264, hm1T, 256, hmb + 256,
                         &sAct[0][0][0], 264, w * 64, lane);
  __syncthreads();
  if (w == 0) mfma_out3<8>(&sAct[0][0][0], 264, hwoT, 256, hbo, sPh, lane);
  __syncthreads();

  if (t < 96) {
    int p = t / 3, ch = t % 3;
    int g = g0 + p;
    int b = g / (HO * WO);
    int rem = g % (HO * WO);
    int oy = rem / WO, ox = rem % WO;
    float gy = coord[(size_t)g * 2 + 0];
    float gx = coord[(size_t)g * 2 + 1];
    float x = (gx + 1.f) * (WL * 0.5f) - 0.5f;
    float y = (gy + 1.f) * (HL * 0.5f) - 0.5f;
    float xf = floorf(x), yf = floorf(y);
    float wx = x - xf, wy = y - yf;
    int x0i = min(max((int)xf,     0), WL - 1);
    int x1i = min(max((int)xf + 1, 0), WL - 1);
    int y0i = min(max((int)yf,     0), HL - 1);
    int y1i = min(max((int)yf + 1, 0), HL - 1);
    const float* img = lr + ((size_t)b * 3 + ch) * (HL * WL);
    float v00 = img[y0i * WL + x0i], v01 = img[y0i * WL + x1i];
    float v10 = img[y1i * WL + x0i], v11 = img[y1i * WL + x1i];
    float v = v00 * (1.f - wx) * (1.f - wy) + v01 * wx * (1.f - wy)
            + v10 * (1.f - wx) * wy + v11 * wx * wy;
    float pr = sHard[p] ? sPh[p][ch] : sPl[p][ch];
    out[(((size_t)b * 3 + ch) * HO + oy) * WO + ox] = pr + v;
  }
}

__global__ void finalize_k(const int* __restrict__ easyCnt, float* __restrict__ out)
{
  out[(size_t)NPIX * 3] = (float)(*easyCnt) / (float)NPIX;
}

// ---------------------------------------------------------------------------
extern "C" void kernel_launch(void* const* d_in, const int* in_sizes, int n_in,
                              void* d_out, int out_size, void* d_ws, size_t ws_size,
                              hipStream_t stream)
{
  const float* lr       = (const float*)d_in[0];
  const float* coord    = (const float*)d_in[1];
  const float* cell     = (const float*)d_in[2];
  const float* enc_w_in = (const float*)d_in[3];
  const float* enc_b_in = (const float*)d_in[4];
  const float* enc_rw   = (const float*)d_in[5];
  const float* enc_rb   = (const float*)d_in[6];
  const float* cw1      = (const float*)d_in[7];
  const float* cb1      = (const float*)d_in[8];
  const float* cw2      = (const float*)d_in[9];
  const float* cb2      = (const float*)d_in[10];
  const float* lw1      = (const float*)d_in[11];
  const float* lb1      = (const float*)d_in[12];
  const float* lw2      = (const float*)d_in[13];
  const float* lb2      = (const float*)d_in[14];
  const float* lw3      = (const float*)d_in[15];
  const float* lb3      = (const float*)d_in[16];
  const float* hw1      = (const float*)d_in[17];
  const float* hb1      = (const float*)d_in[18];
  const float* hmw      = (const float*)d_in[19];
  const float* hmb      = (const float*)d_in[20];
  const float* hwo      = (const float*)d_in[21];
  const float* hbo      = (const float*)d_in[22];
  float* out = (float*)d_out;

  char* ws = (char*)d_ws;
  int*   cnt   = (int*)ws;
  float* xA    = (float*)(ws + 1024);
  float* tmp   = xA  + FEAT_ELEMS;
  float* xB    = tmp + FEAT_ELEMS;
  float* featT = tmp;                 // aliases tmp (free after last res conv)
  unsigned short* wb = (unsigned short*)(xB + FEAT_ELEMS);
  unsigned short* lw1T = wb;              // 64*96
  unsigned short* lw2T = lw1T + 64*96;    // 64*64
  unsigned short* lw3T = lw2T + 64*64;    // 16*64
  unsigned short* hw1T = lw3T + 16*64;    // 256*96
  unsigned short* hm0T = hw1T + 256*96;   // 256*256
  unsigned short* hm1T = hm0T + 65536;    // 256*256
  unsigned short* hwoT = hm1T + 65536;    // 16*256
  const size_t nb16 = 64*96 + 64*64 + 16*64 + 256*96 + 2*65536 + 16*256; // 171008
  float* cwIn  = (float*)(wb + nb16);     // 27*64 = 1728
  float* cwRes = cwIn + 1728;             // 8 * 36864
  size_t need = 1024 + 3 * FEAT_ELEMS * sizeof(float)
              + nb16 * 2 + (1728 + 8 * 36864) * sizeof(float);
  if (ws_size < need) return;

  // --- weight preps ---
  auto prep = [&](const float* s, unsigned short* d, int K, int N, int Kp, int Np) {
    int tot = Kp * Np;
    prep_wt_k<<<(tot + 255) / 256, 256, 0, stream>>>(s, d, K, N, Kp, Np);
  };
  prep(lw1, lw1T, 68, 64, 96, 64);
  prep(lw2, lw2T, 64, 64, 64, 64);
  prep(lw3, lw3T, 64, 3, 64, 16);
  prep(hw1, hw1T, 68, 256, 96, 256);
  prep(hmw,         hm0T, 256, 256, 256, 256);
  prep(hmw + 65536, hm1T, 256, 256, 256, 256);
  prep(hwo, hwoT, 256, 3, 256, 16);

  prep_convw_k<<<(1728 + 255) / 256, 256, 0, stream>>>(enc_w_in, cwIn, 3);
  for (int l = 0; l < 8; ++l)
    prep_convw_k<<<(36864 + 255) / 256, 256, 0, stream>>>(
        enc_rw + (size_t)l * 36864, cwRes + (size_t)l * 36864, 64);

  // --- encoder ---
  dim3 cgrid(36, 16, 2);   // 4 co per thread -> 1152 blocks for latency hiding
  conv_s_k<3, 4, false, false><<<cgrid, 256, 0, stream>>>(lr, cwIn, enc_b_in, nullptr, xA);

  float* cur = xA; float* oth = xB;
  for (int i = 0; i < 4; ++i) {
    const float* wp0 = cwRes + (size_t)(2 * i)     * 36864;
    const float* wp1 = cwRes + (size_t)(2 * i + 1) * 36864;
    const float* b0 = enc_rb + i * 128;
    const float* b1 = b0 + 64;
    conv_s_k<64, 4, true,  false><<<cgrid, 256, 0, stream>>>(cur, wp0, b0, nullptr, tmp);
    conv_s_k<64, 4, false, true ><<<cgrid, 256, 0, stream>>>(tmp, wp1, b1, cur, oth);
    float* sw2 = cur; cur = oth; oth = sw2;
  }

  nchw_to_nhwc_k<<<dim3(144, 2), 256, 0, stream>>>(cur, featT);

  hipMemsetAsync(cnt, 0, 4, stream);
  fused_mlp_k<<<NPIX / 32, 256, 0, stream>>>(featT, coord, cell, lr,
      cw1, cb1, cw2, cb2, lb1, lb2, lb3, hb1, hmb, hbo,
      lw1T, lw2T, lw3T, hw1T, hm0T, hm1T, hwoT, out, cnt);
  finalize_k<<<1, 1, 0, stream>>>(cnt, out);
}

// Round 5
// 707.273 us; speedup vs baseline: 4.3947x; 1.1622x over previous
//
#include <hip/hip_runtime.h>

#define HL 96
#define WL 96
#define HO 384
#define WO 384
#define NPIX (2*HO*WO)           // 294912 output pixels (B=2)
#define FEAT_ELEMS ((size_t)2*64*HL*WL)  // 1179648
#define PLANE (HL*WL)            // 9216

typedef unsigned short us4 __attribute__((ext_vector_type(4)));
typedef unsigned short us8 __attribute__((ext_vector_type(8)));
typedef __bf16         b8  __attribute__((ext_vector_type(8)));
typedef float          f32x4 __attribute__((ext_vector_type(4)));

__device__ __forceinline__ unsigned short f2b(float x) {
  unsigned u = __builtin_bit_cast(unsigned, x);
  unsigned r = (u + 0x7FFFu + ((u >> 16) & 1u)) >> 16;
  return (unsigned short)r;
}

__device__ __forceinline__ f32x4 MF(us8 a, us8 b, f32x4 c) {
  return __builtin_amdgcn_mfma_f32_16x16x32_bf16(
      __builtin_bit_cast(b8, a), __builtin_bit_cast(b8, b), c, 0, 0, 0);
}

// ---------------------------------------------------------------------------
// Scalar-weight direct conv (unchanged, known good)
// ---------------------------------------------------------------------------
template<int CIN, int COPT, bool RELU, bool RES>
__global__ __launch_bounds__(256) void conv_s_k(
    const float* __restrict__ in, const float* __restrict__ wP,
    const float* __restrict__ bias, const float* __restrict__ res,
    float* __restrict__ out)
{
  const int t   = threadIdx.x;
  const int p   = blockIdx.x * 256 + t;
  const int co0 = blockIdx.y * COPT;
  const int b   = blockIdx.z;
  const int x   = p % WL;
  const bool xl = (x == 0), xr = (x == WL - 1);

  float acc[COPT];
  #pragma unroll
  for (int j = 0; j < COPT; ++j) acc[j] = bias[co0 + j];

  int  ic[3]; bool yv[3];
  int  im[3], ip[3];
  #pragma unroll
  for (int ky = 0; ky < 3; ++ky) {
    int pr = p + (ky - 1) * WL;
    yv[ky] = ((unsigned)pr < (unsigned)PLANE);
    ic[ky] = yv[ky] ? pr : 0;
    im[ky] = ic[ky] - 1; if (im[ky] < 0) im[ky] = 0;
    ip[ky] = ic[ky] + 1; if (ip[ky] > PLANE - 1) ip[ky] = PLANE - 1;
  }

  const float* inb = in + (size_t)b * CIN * PLANE;

  for (int ci = 0; ci < CIN; ++ci) {
    const float* pl = inb + (size_t)ci * PLANE;
    #pragma unroll
    for (int ky = 0; ky < 3; ++ky) {
      float am = pl[im[ky]];
      float a0 = pl[ic[ky]];
      float ap = pl[ip[ky]];
      if (!yv[ky]) { am = 0.f; a0 = 0.f; ap = 0.f; }
      if (xl) am = 0.f;
      if (xr) ap = 0.f;
      const float* wrow = wP + (size_t)(ci * 9 + ky * 3) * 64 + co0;
      #pragma unroll
      for (int j = 0; j < COPT; ++j) acc[j] += am * wrow[j];
      #pragma unroll
      for (int j = 0; j < COPT; ++j) acc[j] += a0 * wrow[64 + j];
      #pragma unroll
      for (int j = 0; j < COPT; ++j) acc[j] += ap * wrow[128 + j];
    }
  }

  size_t ob = ((size_t)b * 64 + co0) * PLANE + p;
  #pragma unroll
  for (int j = 0; j < COPT; ++j) {
    float v = acc[j];
    if (RELU) v = fmaxf(v, 0.f);
    if (RES)  v += res[ob + (size_t)j * PLANE];
    out[ob + (size_t)j * PLANE] = v;
  }
}

__global__ __launch_bounds__(256) void prep_convw_k(const float* __restrict__ src,
                                                    float* __restrict__ dst, int cin)
{
  int idx = blockIdx.x * 256 + threadIdx.x;
  int tot = cin * 9 * 64;
  if (idx >= tot) return;
  int co = idx % 64; int r = idx / 64;
  int ci = r / 9, tap = r % 9;
  dst[idx] = src[((size_t)co * cin + ci) * 9 + tap];
}

__global__ __launch_bounds__(256) void nchw_to_nhwc_k(const float* __restrict__ in,
                                                      float* __restrict__ out)
{
  __shared__ float s[64][65];
  const int b = blockIdx.y;
  const int pix0 = blockIdx.x * 64;
  const int t = threadIdx.x;
  #pragma unroll
  for (int cc = 0; cc < 16; ++cc) {
    int co = cc * 4 + (t >> 6);
    int px = t & 63;
    s[px][co] = in[((size_t)b * 64 + co) * PLANE + pix0 + px];
  }
  __syncthreads();
  #pragma unroll
  for (int pp = 0; pp < 16; ++pp) {
    int px = pp * 4 + (t >> 6);
    int co = t & 63;
    out[((size_t)b * PLANE + pix0 + px) * 64 + co] = s[px][co];
  }
}

__global__ __launch_bounds__(256) void prep_wt_k(const float* __restrict__ src,
    unsigned short* __restrict__ dst, int K, int N, int Kpad, int Npad)
{
  int idx = blockIdx.x * 256 + threadIdx.x;
  if (idx >= Kpad * Npad) return;
  int n = idx / Kpad, k = idx - n * Kpad;
  float v = (k < K && n < N) ? src[(size_t)k * N + n] : 0.f;
  dst[idx] = f2b(v);
}

// ---------------------------------------------------------------------------
// fp32 64-wide layer (classifier; 512 threads -> 64 px)
// ---------------------------------------------------------------------------
__device__ __forceinline__ void layer64(const float* src, int sstride,
    const float* __restrict__ W, const float* __restrict__ B,
    float* dst, int dstride, int K, bool relu, int t)
{
  const int p  = t >> 3;          // 0..63
  const int c0 = (t & 7) << 3;
  float acc[8];
  #pragma unroll
  for (int j = 0; j < 8; ++j) acc[j] = B[c0 + j];
  const float* s = src + p * sstride;
  for (int k = 0; k < K; k += 4) {
    float4 a4 = *(const float4*)(s + k);
    float av[4] = {a4.x, a4.y, a4.z, a4.w};
    #pragma unroll
    for (int kk = 0; kk < 4; ++kk) {
      float a = av[kk];
      float4 w0 = *(const float4*)&W[(size_t)(k + kk) * 64 + c0];
      float4 w1 = *(const float4*)&W[(size_t)(k + kk) * 64 + c0 + 4];
      acc[0] += a * w0.x; acc[1] += a * w0.y; acc[2] += a * w0.z; acc[3] += a * w0.w;
      acc[4] += a * w1.x; acc[5] += a * w1.y; acc[6] += a * w1.z; acc[7] += a * w1.w;
    }
  }
  float* d = dst + p * dstride + c0;
  #pragma unroll
  for (int j = 0; j < 8; ++j) d[j] = relu ? fmaxf(acc[j], 0.f) : acc[j];
}

// ---------------------------------------------------------------------------
// MFMA helpers, M=64 geometry: wave computes 64 rows x NT*16 cols.
// Compute and store are SPLIT so the caller can place a barrier between the
// last read of sAct and the in-place write (single-buffer discipline).
// ---------------------------------------------------------------------------
template<int NT, int KT>
__device__ __forceinline__ void mfma_compute(
    const unsigned short* __restrict__ aBase, int AS,
    const unsigned short* __restrict__ WT, int Kpad,
    int n0, int lane, f32x4 (&acc)[4][NT])
{
  const int lr = lane & 15;
  const int lc = lane >> 4;
  #pragma unroll
  for (int m = 0; m < 4; ++m)
    #pragma unroll
    for (int j = 0; j < NT; ++j) acc[m][j] = (f32x4){0.f, 0.f, 0.f, 0.f};

  const unsigned short* aP = aBase + lr * AS + lc * 8;
  const unsigned short* bP = WT + (size_t)(n0 + lr) * Kpad + lc * 8;

  constexpr int KCH = (KT >= 4) ? 4 : KT;
  #pragma unroll
  for (int kc = 0; kc < KT; kc += KCH) {
    us8 breg[KCH][NT];
    #pragma unroll
    for (int kk = 0; kk < KCH; ++kk)
      #pragma unroll
      for (int j = 0; j < NT; ++j)
        breg[kk][j] = *(const us8*)(bP + (size_t)j * 16 * Kpad + (kc + kk) * 32);
    #pragma unroll
    for (int kk = 0; kk < KCH; ++kk) {
      us8 a0[4];
      #pragma unroll
      for (int m = 0; m < 4; ++m)
        a0[m] = *(const us8*)(aP + (m * 16) * AS + (kc + kk) * 32);
      #pragma unroll
      for (int m = 0; m < 4; ++m)
        #pragma unroll
        for (int j = 0; j < NT; ++j)
          acc[m][j] = MF(a0[m], breg[kk][j], acc[m][j]);
    }
  }
}

template<int NT, bool RELU>
__device__ __forceinline__ void mfma_store(
    const f32x4 (&acc)[4][NT], const float* __restrict__ bias,
    unsigned short* __restrict__ dBase, int DS, int dCol0, int n0, int lane)
{
  const int lr = lane & 15;
  const int lc = lane >> 4;
  #pragma unroll
  for (int j = 0; j < NT; ++j) {
    int n = n0 + j * 16 + lr;
    float bv = bias[n];
    #pragma unroll
    for (int m = 0; m < 4; ++m)
      #pragma unroll
      for (int r = 0; r < 4; ++r) {
        float v = acc[m][j][r] + bv;
        if (RELU) v = fmaxf(v, 0.f);
        dBase[(m * 16 + lc * 4 + r) * DS + dCol0 + n] = f2b(v);
      }
  }
}

// N=16 tile (3 real cols); wave handles m-tile `mtile`
template<int KT>
__device__ __forceinline__ void mfma_out3w(
    const unsigned short* __restrict__ aBase, int AS,
    const unsigned short* __restrict__ WT, int Kpad,
    const float* __restrict__ bias, float (*dst)[4], int mtile, int lane)
{
  const int lr = lane & 15;
  const int lc = lane >> 4;
  f32x4 acc = (f32x4){0.f, 0.f, 0.f, 0.f};
  const unsigned short* aP = aBase + (mtile * 16 + lr) * AS + lc * 8;
  const unsigned short* bP = WT + (size_t)lr * Kpad + lc * 8;

  constexpr int KCH = (KT >= 4) ? 4 : KT;
  #pragma unroll
  for (int kc = 0; kc < KT; kc += KCH) {
    us8 breg[KCH];
    #pragma unroll
    for (int kk = 0; kk < KCH; ++kk)
      breg[kk] = *(const us8*)(bP + (kc + kk) * 32);
    #pragma unroll
    for (int kk = 0; kk < KCH; ++kk) {
      us8 a = *(const us8*)(aP + (kc + kk) * 32);
      acc = MF(a, breg[kk], acc);
    }
  }
  if (lr < 3) {
    float bv = bias[lr];
    #pragma unroll
    for (int r = 0; r < 4; ++r)
      dst[mtile * 16 + lc * 4 + r][lr] = acc[r] + bv;
  }
}

// ---------------------------------------------------------------------------
// Fused per-pixel pipeline: 64 pixels / block, 512 threads (8 waves)
// Single activation buffer; heavy-mid layers hold D in registers across the
// write barrier. LDS ~68KB -> 2 blocks/CU -> 4 waves/SIMD.
// ---------------------------------------------------------------------------
__global__ __launch_bounds__(512, 4) void fused_mlp_k(
    const float* __restrict__ featT, const float* __restrict__ coord,
    const float* __restrict__ cell,  const float* __restrict__ lr,
    const float* __restrict__ cw1, const float* __restrict__ cb1,
    const float* __restrict__ cw2, const float* __restrict__ cb2,
    const float* __restrict__ lb1, const float* __restrict__ lb2,
    const float* __restrict__ lb3, const float* __restrict__ hb1,
    const float* __restrict__ hmb, const float* __restrict__ hbo,
    const unsigned short* __restrict__ lw1T, const unsigned short* __restrict__ lw2T,
    const unsigned short* __restrict__ lw3T, const unsigned short* __restrict__ hw1T,
    const unsigned short* __restrict__ hm0T, const unsigned short* __restrict__ hm1T,
    const unsigned short* __restrict__ hwoT,
    float* __restrict__ out, int* __restrict__ easyCnt)
{
  __shared__ unsigned short sAct[64][264];   // 33.8 KB single activation buffer
  __shared__ unsigned short sInpB[64][104];  // 13.3 KB bf16 inp (K padded 96)
  __shared__ float          sInpF[64][72];   // 18.4 KB fp32 inp (classifier)
  __shared__ float sPl[64][4];
  __shared__ float sPh[64][4];
  __shared__ int   sHard[64];

  const int t    = threadIdx.x;
  const int lane = t & 63;
  const int w    = t >> 6;
  const int g0   = blockIdx.x * 64;
  float* clsH = (float*)&sAct[0][0];         // fp32 [64][66] overlay (pre-light)

  // ---- Phase A: build inp ----
  {
    const int p = t >> 3;        // pixel 0..63
    const int q = t & 7;         // 8-channel chunk
    const int g = g0 + p;
    const int b = g / (HO * WO);
    const float gy = coord[(size_t)g * 2 + 0];
    const float gx = coord[(size_t)g * 2 + 1];
    float fy = (gy + 1.f) * (HL * 0.5f) - 0.5f;
    float fx = (gx + 1.f) * (WL * 0.5f) - 0.5f;
    int iy = min(max((int)floorf(fy + 0.5f), 0), HL - 1);
    int ix = min(max((int)floorf(fx + 0.5f), 0), WL - 1);
    const float* fp = featT + (((size_t)b * PLANE) + iy * WL + ix) * 64 + q * 8;
    float4 u0 = *(const float4*)fp;
    float4 u1 = *(const float4*)(fp + 4);
    *(float4*)&sInpF[p][q * 8]     = u0;
    *(float4*)&sInpF[p][q * 8 + 4] = u1;
    us8 pk;
    pk[0]=f2b(u0.x); pk[1]=f2b(u0.y); pk[2]=f2b(u0.z); pk[3]=f2b(u0.w);
    pk[4]=f2b(u1.x); pk[5]=f2b(u1.y); pk[6]=f2b(u1.z); pk[7]=f2b(u1.w);
    *(us8*)&sInpB[p][q * 8] = pk;
    if (q == 0) {
      float cy = (2.f * iy + 1.f) / HL - 1.f;
      float cx = (2.f * ix + 1.f) / WL - 1.f;
      float e0 = (gy - cy) * HL, e1 = (gx - cx) * WL;
      float e2 = cell[(size_t)g * 2 + 0] * HL, e3 = cell[(size_t)g * 2 + 1] * WL;
      sInpF[p][64] = e0; sInpF[p][65] = e1; sInpF[p][66] = e2; sInpF[p][67] = e3;
      us4 pe; pe[0]=f2b(e0); pe[1]=f2b(e1); pe[2]=f2b(e2); pe[3]=f2b(e3);
      *(us4*)&sInpB[p][64] = pe;
    }
    if (q == 1) {
      us4 z = (us4){0,0,0,0};
      #pragma unroll
      for (int c = 0; c < 9; ++c) *(us4*)&sInpB[p][68 + c * 4] = z;
    }
  }
  __syncthreads();

  // ---- Classifier (fp32, exact gate) ----
  layer64(&sInpF[0][0], 72, cw1, cb1, clsH, 66, 68, true, t);
  __syncthreads();
  if (t < 64) {
    float l0 = cb2[0], l1 = cb2[1];
    for (int c = 0; c < 64; ++c) {
      float h = clsH[t * 66 + c];
      l0 += h * cw2[c * 2 + 0];
      l1 += h * cw2[c * 2 + 1];
    }
    sHard[t] = (l1 > l0) ? 1 : 0;
  }
  __syncthreads();
  if (t == 0) {
    int cnt = 0;
    for (int p = 0; p < 64; ++p) cnt += 1 - sHard[p];
    atomicAdd(easyCnt, cnt);
  }

  // ---- Light sampler (waves 0-3; columns of sAct used as l1->0:64, l2->64:128)
  if (w < 4) {
    f32x4 acc[4][1];
    mfma_compute<1, 3>(&sInpB[0][0], 104, lw1T, 96, w * 16, lane, acc);
    mfma_store<1, true>(acc, lb1, &sAct[0][0], 264, 0, w * 16, lane);
  }
  __syncthreads();
  if (w < 4) {
    f32x4 acc[4][1];
    mfma_compute<1, 2>(&sAct[0][0], 264, lw2T, 64, w * 16, lane, acc);
    mfma_store<1, true>(acc, lb2, &sAct[0][0], 264, 64, w * 16, lane); // disjoint cols
  }
  __syncthreads();
  if (w < 4) mfma_out3w<2>(&sAct[0][64], 264, lw3T, 64, lb3, sPl, w, lane);
  __syncthreads();

  // ---- Heavy sampler (all 8 waves; n-slice = w*32, NT=2) ----
  {
    f32x4 acc[4][2];
    mfma_compute<2, 3>(&sInpB[0][0], 104, hw1T, 96, w * 32, lane, acc);
    mfma_store<2, true>(acc, hb1, &sAct[0][0], 264, 0, w * 32, lane);
  }
  __syncthreads();
  {
    f32x4 acc[4][2];
    mfma_compute<2, 8>(&sAct[0][0], 264, hm0T, 256, w * 32, lane, acc);
    __syncthreads();                                   // all reads done
    mfma_store<2, true>(acc, hmb, &sAct[0][0], 264, 0, w * 32, lane);
  }
  __syncthreads();
  {
    f32x4 acc[4][2];
    mfma_compute<2, 8>(&sAct[0][0], 264, hm1T, 256, w * 32, lane, acc);
    __syncthreads();
    mfma_store<2, true>(acc, hmb + 256, &sAct[0][0], 264, 0, w * 32, lane);
  }
  __syncthreads();
  if (w < 4) mfma_out3w<8>(&sAct[0][0], 264, hwoT, 256, hbo, sPh, w, lane);
  __syncthreads();

  // ---- Epilogue: gated select + bilinear(lr) ----
  if (t < 192) {
    int p = t / 3, ch = t % 3;
    int g = g0 + p;
    int b = g / (HO * WO);
    int rem = g % (HO * WO);
    int oy = rem / WO, ox = rem % WO;
    float gy = coord[(size_t)g * 2 + 0];
    float gx = coord[(size_t)g * 2 + 1];
    float x = (gx + 1.f) * (WL * 0.5f) - 0.5f;
    float y = (gy + 1.f) * (HL * 0.5f) - 0.5f;
    float xf = floorf(x), yf = floorf(y);
    float wx = x - xf, wy = y - yf;
    int x0i = min(max((int)xf,     0), WL - 1);
    int x1i = min(max((int)xf + 1, 0), WL - 1);
    int y0i = min(max((int)yf,     0), HL - 1);
    int y1i = min(max((int)yf + 1, 0), HL - 1);
    const float* img = lr + ((size_t)b * 3 + ch) * PLANE;
    float v00 = img[y0i * WL + x0i], v01 = img[y0i * WL + x1i];
    float v10 = img[y1i * WL + x0i], v11 = img[y1i * WL + x1i];
    float v = v00 * (1.f - wx) * (1.f - wy) + v01 * wx * (1.f - wy)
            + v10 * (1.f - wx) * wy + v11 * wx * wy;
    float pr = sHard[p] ? sPh[p][ch] : sPl[p][ch];
    out[(((size_t)b * 3 + ch) * HO + oy) * WO + ox] = pr + v;
  }
}

__global__ void finalize_k(const int* __restrict__ easyCnt, float* __restrict__ out)
{
  out[(size_t)NPIX * 3] = (float)(*easyCnt) / (float)NPIX;
}

// ---------------------------------------------------------------------------
extern "C" void kernel_launch(void* const* d_in, const int* in_sizes, int n_in,
                              void* d_out, int out_size, void* d_ws, size_t ws_size,
                              hipStream_t stream)
{
  const float* lr       = (const float*)d_in[0];
  const float* coord    = (const float*)d_in[1];
  const float* cell     = (const float*)d_in[2];
  const float* enc_w_in = (const float*)d_in[3];
  const float* enc_b_in = (const float*)d_in[4];
  const float* enc_rw   = (const float*)d_in[5];
  const float* enc_rb   = (const float*)d_in[6];
  const float* cw1      = (const float*)d_in[7];
  const float* cb1      = (const float*)d_in[8];
  const float* cw2      = (const float*)d_in[9];
  const float* cb2      = (const float*)d_in[10];
  const float* lw1      = (const float*)d_in[11];
  const float* lb1      = (const float*)d_in[12];
  const float* lw2      = (const float*)d_in[13];
  const float* lb2      = (const float*)d_in[14];
  const float* lw3      = (const float*)d_in[15];
  const float* lb3      = (const float*)d_in[16];
  const float* hw1      = (const float*)d_in[17];
  const float* hb1      = (const float*)d_in[18];
  const float* hmw      = (const float*)d_in[19];
  const float* hmb      = (const float*)d_in[20];
  const float* hwo      = (const float*)d_in[21];
  const float* hbo      = (const float*)d_in[22];
  float* out = (float*)d_out;

  char* ws = (char*)d_ws;
  int*   cnt   = (int*)ws;
  float* xA    = (float*)(ws + 1024);
  float* tmp   = xA  + FEAT_ELEMS;
  float* xB    = tmp + FEAT_ELEMS;
  float* featT = tmp;                 // aliases tmp (free after last res conv)
  unsigned short* wb = (unsigned short*)(xB + FEAT_ELEMS);
  unsigned short* lw1T = wb;              // 64*96
  unsigned short* lw2T = lw1T + 64*96;    // 64*64
  unsigned short* lw3T = lw2T + 64*64;    // 16*64
  unsigned short* hw1T = lw3T + 16*64;    // 256*96
  unsigned short* hm0T = hw1T + 256*96;   // 256*256
  unsigned short* hm1T = hm0T + 65536;    // 256*256
  unsigned short* hwoT = hm1T + 65536;    // 16*256
  const size_t nb16 = 64*96 + 64*64 + 16*64 + 256*96 + 2*65536 + 16*256; // 171008
  float* cwIn  = (float*)(wb + nb16);     // 27*64 = 1728
  float* cwRes = cwIn + 1728;             // 8 * 36864
  size_t need = 1024 + 3 * FEAT_ELEMS * sizeof(float)
              + nb16 * 2 + (1728 + 8 * 36864) * sizeof(float);
  if (ws_size < need) return;

  auto prep = [&](const float* s, unsigned short* d, int K, int N, int Kp, int Np) {
    int tot = Kp * Np;
    prep_wt_k<<<(tot + 255) / 256, 256, 0, stream>>>(s, d, K, N, Kp, Np);
  };
  prep(lw1, lw1T, 68, 64, 96, 64);
  prep(lw2, lw2T, 64, 64, 64, 64);
  prep(lw3, lw3T, 64, 3, 64, 16);
  prep(hw1, hw1T, 68, 256, 96, 256);
  prep(hmw,         hm0T, 256, 256, 256, 256);
  prep(hmw + 65536, hm1T, 256, 256, 256, 256);
  prep(hwo, hwoT, 256, 3, 256, 16);

  prep_convw_k<<<(1728 + 255) / 256, 256, 0, stream>>>(enc_w_in, cwIn, 3);
  for (int l = 0; l < 8; ++l)
    prep_convw_k<<<(36864 + 255) / 256, 256, 0, stream>>>(
        enc_rw + (size_t)l * 36864, cwRes + (size_t)l * 36864, 64);

  dim3 cgrid(36, 16, 2);
  conv_s_k<3, 4, false, false><<<cgrid, 256, 0, stream>>>(lr, cwIn, enc_b_in, nullptr, xA);

  float* cur = xA; float* oth = xB;
  for (int i = 0; i < 4; ++i) {
    const float* wp0 = cwRes + (size_t)(2 * i)     * 36864;
    const float* wp1 = cwRes + (size_t)(2 * i + 1) * 36864;
    const float* b0 = enc_rb + i * 128;
    const float* b1 = b0 + 64;
    conv_s_k<64, 4, true,  false><<<cgrid, 256, 0, stream>>>(cur, wp0, b0, nullptr, tmp);
    conv_s_k<64, 4, false, true ><<<cgrid, 256, 0, stream>>>(tmp, wp1, b1, cur, oth);
    float* sw2 = cur; cur = oth; oth = sw2;
  }

  nchw_to_nhwc_k<<<dim3(144, 2), 256, 0, stream>>>(cur, featT);

  hipMemsetAsync(cnt, 0, 4, stream);
  fused_mlp_k<<<NPIX / 64, 512, 0, stream>>>(featT, coord, cell, lr,
      cw1, cb1, cw2, cb2, lb1, lb2, lb3, hb1, hmb, hbo,
      lw1T, lw2T, lw3T, hw1T, hm0T, hm1T, hwoT, out, cnt);
  finalize_k<<<1, 1, 0, stream>>>(cnt, out);
}